// Round 8
// baseline (1108.941 us; speedup 1.0000x reference)
//
#include <hip/hip_runtime.h>

// ComplexNetAttention on gfx950.
// Pipeline: int8-fakequant -> fused complex QKV GEMM (fp16 MFMA, NT, K=4096;
//   8-phase counted-vmcnt schedule, 256x192 tile) -> cos/sin table +
//   vectorized RoPE -> fused flash attention v2 (KBLK=128, R12: 4 blocks/CU) ->
//   fakequant -> out GEMM (256x128 8-phase counted-vmcnt).
//
// R12: flash_attn unchanged from R7 EXCEPT __launch_bounds__(256,2)->(256,4):
// 4 independent blocks/CU instead of 2. R3's occupancy attempt failed because
// it also halved per-stage work (doubled stage count); this isolates pure TLP
// on the proven KBLK=128 structure. Blocks are independent -> during one
// block's barrier rendezvous / K-V load latency the SIMD issues other blocks'
// waves (m114). LDS 18.4KB x4 = 74KB < 160KB; VGPR 116 <= 128 cap.

typedef float v4f __attribute__((ext_vector_type(4)));
typedef _Float16 v8h __attribute__((ext_vector_type(8)));
typedef _Float16 v4h __attribute__((ext_vector_type(4)));

typedef const __attribute__((address_space(1))) void glob_void;
typedef __attribute__((address_space(3))) void lds_void;

__device__ __forceinline__ void gload16(const _Float16* gp, _Float16* lp) {
  __builtin_amdgcn_global_load_lds((glob_void*)gp, (lds_void*)lp, 16, 0, 0);
}

// bf16 round-trip (RNE) in fp32 — matches reference's bf16 cos/sin cache.
__device__ __forceinline__ float bf16_rt(float f) {
  union { float f; unsigned u; } a; a.f = f;
  unsigned r = (a.u + 0x7fffu + ((a.u >> 16) & 1u)) & 0xffff0000u;
  union { unsigned u; float f; } b; b.u = r;
  return b.f;
}

#define SBAR()  __builtin_amdgcn_sched_barrier(0)
#define WBAR()  __builtin_amdgcn_s_barrier()
#define LGKM0() asm volatile("s_waitcnt lgkmcnt(0)" ::: "memory")

// ---------------------------------------------------------------------------
// QKV GEMM: C[2048][12288] = A[2048][4096] @ B[12288][4096]^T, fp16, fp32 acc.
// Tile 256x192, BK=64, 512 thr (8 waves 2m x 4n), wave-tile 128x48.
// 8-phase counted-vmcnt schedule (T3+T4), XOR chunk swizzle (0-conflict),
// s_setprio around MFMA clusters (T5), bijective XCD chunking (T1).
// ---------------------------------------------------------------------------
__global__ __launch_bounds__(512, 2) void gemm_qkv256(
    const _Float16* __restrict__ A, const _Float16* __restrict__ B,
    _Float16* __restrict__ Yq, _Float16* __restrict__ vt)
{
  const int p = blockIdx.x;            // 0..511, XCD = p & 7 (round-robin)
  const int xcd = p & 7, s = p >> 3;   // s: 0..63 within chunk
  const int mt = s & 7, ntl = s >> 3;
  const int nt = xcd * 8 + ntl;        // 0..63
  const int m0 = mt << 8;              // *256
  const int n0 = nt * 192;

  __shared__ __align__(16) _Float16 lds[57344];  // 2 bufs x (16384 A + 12288 B)

  const int tid = threadIdx.x, lane = tid & 63, wave = tid >> 6;
  const int quad = lane >> 4, l15 = lane & 15;
  const int wm = wave >> 2, wn = wave & 3;       // 2 x 4 waves

  // staging constants: for gload j covering LDS halfs [j*4096 + tid*8):
  // r = (j&1)*128 + tid>>2, pc = tid&3, lc = pc ^ ((r>>1)&3)
  const int rr = tid >> 2;                                   // 0..127
  const int lc8 = (((tid & 3) ^ ((tid >> 3) & 3)) << 3);     // logical chunk*8
  const _Float16* gA = A + (long long)(m0 + rr) * 4096 + lc8;
  // B tile = 24KB = 3 gloads; gload 1 crosses the ks0/ks1 subtile boundary.
  const _Float16* gBj[3];
#pragma unroll
  for (int j = 0; j < 3; ++j) {
    const int ks = (j == 2) || (j == 1 && tid >= 256);
    const int r = j * 128 + (tid >> 2) - ks * 192;
    gBj[j] = B + (long long)(n0 + r) * 4096 + ks * 32 + lc8;
  }

  // read constants: phys chunk = quad ^ ((l15>>1)&3), constant per lane
  const int co = ((quad ^ ((l15 >> 1) & 3)) << 3);
  const int aBase = (wm * 128 + l15) * 32 + co;
  const int bBase = (wn * 48 + l15) * 32 + co;

  v4f acc[8][3] = {};

  // prologue: stage tile 0 -> buf 0 in canonical order a0,a1,b0,b1,a2,a3,b2
  {
    _Float16* sd = lds + tid * 8;
    gload16(gA, sd);
    gload16(gA + 524288, sd + 4096);          // 128*4096
    gload16(gBj[0], sd + 16384);
    gload16(gBj[1], sd + 20480);
    gload16(gA + 32, sd + 8192);
    gload16(gA + 524288 + 32, sd + 12288);
    gload16(gBj[2], sd + 24576);
  }
  asm volatile("s_waitcnt vmcnt(3)" ::: "memory");  // first-4 of tile 0 done
  WBAR();

  for (int t = 0; t < 64; ++t) {
    const _Float16* As = lds + (t & 1) * 28672;
    const _Float16* Bs = As + 16384;
    _Float16* sd = lds + ((t & 1) ^ 1) * 28672 + tid * 8;
    const int k1 = (t + 1) << 6;
    const bool stg = (t < 63);

    v8h bf[3], af[4];

    // ===== P0: ds bf(ks0)+af(mh0,ks0); stage a0,a1(t+1) =====
    af[0] = *(const v8h*)&As[aBase];
    af[1] = *(const v8h*)&As[aBase + 512];
    af[2] = *(const v8h*)&As[aBase + 1024];
    af[3] = *(const v8h*)&As[aBase + 1536];
    bf[0] = *(const v8h*)&Bs[bBase];
    bf[1] = *(const v8h*)&Bs[bBase + 512];
    bf[2] = *(const v8h*)&Bs[bBase + 1024];
    if (stg) { gload16(gA + k1, sd); gload16(gA + k1 + 524288, sd + 4096); }
    SBAR(); WBAR(); LGKM0(); SBAR();
    __builtin_amdgcn_s_setprio(1);
#pragma unroll
    for (int i = 0; i < 4; ++i)
#pragma unroll
      for (int nf = 0; nf < 3; ++nf)
        acc[i][nf] = __builtin_amdgcn_mfma_f32_16x16x32_f16(af[i], bf[nf], acc[i][nf], 0, 0, 0);
    __builtin_amdgcn_s_setprio(0);
    WBAR();

    // ===== P1: ds af(mh1,ks0); stage b0,b1(t+1); vmcnt(4) =====
    af[0] = *(const v8h*)&As[aBase + 2048];
    af[1] = *(const v8h*)&As[aBase + 2560];
    af[2] = *(const v8h*)&As[aBase + 3072];
    af[3] = *(const v8h*)&As[aBase + 3584];
    if (stg) { gload16(gBj[0] + k1, sd + 16384); gload16(gBj[1] + k1, sd + 20480); }
    SBAR(); WBAR(); LGKM0(); SBAR();
    __builtin_amdgcn_s_setprio(1);
#pragma unroll
    for (int i = 0; i < 4; ++i)
#pragma unroll
      for (int nf = 0; nf < 3; ++nf)
        acc[4 + i][nf] = __builtin_amdgcn_mfma_f32_16x16x32_f16(af[i], bf[nf], acc[4 + i][nf], 0, 0, 0);
    __builtin_amdgcn_s_setprio(0);
    if (stg) asm volatile("s_waitcnt vmcnt(4)" ::: "memory");
    else     asm volatile("s_waitcnt vmcnt(0)" ::: "memory");
    WBAR();

    // ===== P2: ds bf(ks1)+af(mh0,ks1); stage a2,a3(t+1) =====
    bf[0] = *(const v8h*)&Bs[bBase + 6144];
    bf[1] = *(const v8h*)&Bs[bBase + 6656];
    bf[2] = *(const v8h*)&Bs[bBase + 7168];
    af[0] = *(const v8h*)&As[aBase + 8192];
    af[1] = *(const v8h*)&As[aBase + 8704];
    af[2] = *(const v8h*)&As[aBase + 9216];
    af[3] = *(const v8h*)&As[aBase + 9728];
    if (stg) { gload16(gA + k1 + 32, sd + 8192); gload16(gA + k1 + 524288 + 32, sd + 12288); }
    SBAR(); WBAR(); LGKM0(); SBAR();
    __builtin_amdgcn_s_setprio(1);
#pragma unroll
    for (int i = 0; i < 4; ++i)
#pragma unroll
      for (int nf = 0; nf < 3; ++nf)
        acc[i][nf] = __builtin_amdgcn_mfma_f32_16x16x32_f16(af[i], bf[nf], acc[i][nf], 0, 0, 0);
    __builtin_amdgcn_s_setprio(0);
    WBAR();

    // ===== P3: ds af(mh1,ks1); stage b2(t+1); vmcnt(3) =====
    af[0] = *(const v8h*)&As[aBase + 10240];
    af[1] = *(const v8h*)&As[aBase + 10752];
    af[2] = *(const v8h*)&As[aBase + 11264];
    af[3] = *(const v8h*)&As[aBase + 11776];
    if (stg) gload16(gBj[2] + k1, sd + 24576);
    SBAR(); WBAR(); LGKM0(); SBAR();
    __builtin_amdgcn_s_setprio(1);
#pragma unroll
    for (int i = 0; i < 4; ++i)
#pragma unroll
      for (int nf = 0; nf < 3; ++nf)
        acc[4 + i][nf] = __builtin_amdgcn_mfma_f32_16x16x32_f16(af[i], bf[nf], acc[4 + i][nf], 0, 0, 0);
    __builtin_amdgcn_s_setprio(0);
    if (stg) asm volatile("s_waitcnt vmcnt(3)" ::: "memory");
    WBAR();
  }

  // epilogue: C/D layout col=lane&15, row=quad*4+reg (m89/m91-verified)
#pragma unroll
  for (int mf = 0; mf < 8; ++mf) {
#pragma unroll
    for (int nf = 0; nf < 3; ++nf) {
      const int col = n0 + wn * 48 + nf * 16 + l15;
      const int row0 = m0 + wm * 128 + mf * 16 + quad * 4;   // multiple of 4
      if (col >= 8192) {
        // v projection -> vt[NH][256][2048], packed 4 rows per store
        const int c = col - 8192;
        const int hh = (c & 2047) >> 7;
        const int dcol = (c < 2048) ? (c & 127) : (128 + (c & 127));
        v4h pk;
#pragma unroll
        for (int r = 0; r < 4; ++r) pk[r] = (_Float16)acc[mf][nf][r];
        *(v4h*)(vt + ((long long)(hh * 256 + dcol)) * 2048 + row0) = pk;
      } else {
#pragma unroll
        for (int r = 0; r < 4; ++r)
          Yq[(long long)(row0 + r) * 8192 + col] = (_Float16)acc[mf][nf][r];
      }
    }
  }
}

// ---------------------------------------------------------------------------
// Out GEMM: O[2048][4096] = A[2048][4096] @ B[4096][4096]^T, fp32 out,
// split cols [yr|yi] into concatenated halves of d_out.
// 256x128 tile, BK=64, 8-phase counted-vmcnt (proven R10). Grid 256 = 1/CU.
// ---------------------------------------------------------------------------
__global__ __launch_bounds__(512, 2) void gemm_out256(
    const _Float16* __restrict__ A, const _Float16* __restrict__ B,
    float* __restrict__ O)
{
  const int p = blockIdx.x;            // 0..255
  const int xcd = p & 7, s = p >> 3;   // s: 0..31
  const int mt = s & 7, ntl = s >> 3;  // 8 m-tiles, 4 n-tiles per XCD
  const int nt = xcd * 4 + ntl;        // 0..31
  const int m0 = mt << 8, n0 = nt << 7;

  __shared__ __align__(16) _Float16 lds[49152];  // 2 bufs x (16384 A + 8192 B)

  const int tid = threadIdx.x, lane = tid & 63, wave = tid >> 6;
  const int quad = lane >> 4, l15 = lane & 15;
  const int wm = wave >> 2, wn = wave & 3;       // 2 x 4 waves

  const int rr = tid >> 2;                                   // 0..127
  const int lc8 = (((tid & 3) ^ ((tid >> 3) & 3)) << 3);     // logical chunk*8
  const _Float16* gA = A + (long long)(m0 + rr) * 4096 + lc8;
  const _Float16* gB = B + (long long)(n0 + rr) * 4096 + lc8;

  const int co = ((quad ^ ((l15 >> 1) & 3)) << 3);
  const int aBase = (wm * 128 + l15) * 32 + co;
  const int bBase = (wn * 32 + l15) * 32 + co;

  v4f acc[8][2] = {};

  // prologue: stage tile 0 -> buf 0, first-half trio first
  {
    _Float16* sd = lds + tid * 8;
    gload16(gA, sd);                        // a0: rows 0-127, ks0
    gload16(gA + 524288, sd + 4096);        // a1: rows 128-255, ks0
    gload16(gB, sd + 16384);                // b0: ks0
    gload16(gA + 32, sd + 8192);            // a2: rows 0-127, ks1
    gload16(gA + 524288 + 32, sd + 12288);  // a3: rows 128-255, ks1
    gload16(gB + 32, sd + 20480);           // b1: ks1
  }
  asm volatile("s_waitcnt vmcnt(3)" ::: "memory");  // first trio of tile 0
  WBAR();

  for (int t = 0; t < 64; ++t) {
    const _Float16* As = lds + (t & 1) * 24576;
    const _Float16* Bs = As + 16384;
    _Float16* sd = lds + ((t & 1) ^ 1) * 24576 + tid * 8;
    const int k1 = (t + 1) << 6;
    const bool stg = (t < 63);

    v8h bf[2], af[4];

    // ===== P0: ds af(mh0,ks0)+bf(ks0); stage a0,a1(t+1) =====
    af[0] = *(const v8h*)&As[aBase];
    af[1] = *(const v8h*)&As[aBase + 512];
    af[2] = *(const v8h*)&As[aBase + 1024];
    af[3] = *(const v8h*)&As[aBase + 1536];
    bf[0] = *(const v8h*)&Bs[bBase];
    bf[1] = *(const v8h*)&Bs[bBase + 512];
    if (stg) { gload16(gA + k1, sd); gload16(gA + k1 + 524288, sd + 4096); }
    SBAR(); WBAR(); LGKM0(); SBAR();
    __builtin_amdgcn_s_setprio(1);
#pragma unroll
    for (int i = 0; i < 4; ++i)
#pragma unroll
      for (int nf = 0; nf < 2; ++nf)
        acc[i][nf] = __builtin_amdgcn_mfma_f32_16x16x32_f16(af[i], bf[nf], acc[i][nf], 0, 0, 0);
    __builtin_amdgcn_s_setprio(0);
    WBAR();

    // ===== P1: ds af(mh1,ks0); stage b0(t+1); vmcnt(3) =====
    af[0] = *(const v8h*)&As[aBase + 2048];
    af[1] = *(const v8h*)&As[aBase + 2560];
    af[2] = *(const v8h*)&As[aBase + 3072];
    af[3] = *(const v8h*)&As[aBase + 3584];
    if (stg) gload16(gB + k1, sd + 16384);
    SBAR(); WBAR(); LGKM0(); SBAR();
    __builtin_amdgcn_s_setprio(1);
#pragma unroll
    for (int i = 0; i < 4; ++i)
#pragma unroll
      for (int nf = 0; nf < 2; ++nf)
        acc[4 + i][nf] = __builtin_amdgcn_mfma_f32_16x16x32_f16(af[i], bf[nf], acc[4 + i][nf], 0, 0, 0);
    __builtin_amdgcn_s_setprio(0);
    // retire this tile's ks1 trio {a2,a3,b1}; leave t+1's first trio in flight
    if (stg) asm volatile("s_waitcnt vmcnt(3)" ::: "memory");
    else     asm volatile("s_waitcnt vmcnt(0)" ::: "memory");
    WBAR();

    // ===== P2: ds bf(ks1)+af(mh0,ks1); stage a2,a3(t+1) =====
    bf[0] = *(const v8h*)&Bs[bBase + 4096];
    bf[1] = *(const v8h*)&Bs[bBase + 4608];
    af[0] = *(const v8h*)&As[aBase + 8192];
    af[1] = *(const v8h*)&As[aBase + 8704];
    af[2] = *(const v8h*)&As[aBase + 9216];
    af[3] = *(const v8h*)&As[aBase + 9728];
    if (stg) { gload16(gA + k1 + 32, sd + 8192); gload16(gA + k1 + 524288 + 32, sd + 12288); }
    SBAR(); WBAR(); LGKM0(); SBAR();
    __builtin_amdgcn_s_setprio(1);
#pragma unroll
    for (int i = 0; i < 4; ++i)
#pragma unroll
      for (int nf = 0; nf < 2; ++nf)
        acc[i][nf] = __builtin_amdgcn_mfma_f32_16x16x32_f16(af[i], bf[nf], acc[i][nf], 0, 0, 0);
    __builtin_amdgcn_s_setprio(0);
    WBAR();

    // ===== P3: ds af(mh1,ks1); stage b1(t+1); vmcnt(3) =====
    af[0] = *(const v8h*)&As[aBase + 10240];
    af[1] = *(const v8h*)&As[aBase + 10752];
    af[2] = *(const v8h*)&As[aBase + 11264];
    af[3] = *(const v8h*)&As[aBase + 11776];
    if (stg) gload16(gB + k1 + 32, sd + 20480);
    SBAR(); WBAR(); LGKM0(); SBAR();
    __builtin_amdgcn_s_setprio(1);
#pragma unroll
    for (int i = 0; i < 4; ++i)
#pragma unroll
      for (int nf = 0; nf < 2; ++nf)
        acc[4 + i][nf] = __builtin_amdgcn_mfma_f32_16x16x32_f16(af[i], bf[nf], acc[4 + i][nf], 0, 0, 0);
    __builtin_amdgcn_s_setprio(0);
    // retire t+1's first trio {a0,a1,b0}; leave its ks1 trio in flight
    if (stg) asm volatile("s_waitcnt vmcnt(3)" ::: "memory");
    WBAR();
  }

  // epilogue: fp32, split cols [yr|yi] into concatenated halves of d_out
#pragma unroll
  for (int mf = 0; mf < 8; ++mf) {
#pragma unroll
    for (int nf = 0; nf < 2; ++nf) {
      const int col = n0 + wn * 32 + nf * 16 + l15;
      const int row0 = m0 + wm * 128 + mf * 16 + quad * 4;
#pragma unroll
      for (int r = 0; r < 4; ++r) {
        const int row = row0 + r;
        const float v = acc[mf][nf][r];
        if (col < 2048) O[(long long)row * 2048 + col] = v;
        else O[2048ll * 2048 + (long long)row * 2048 + (col - 2048)] = v;
      }
    }
  }
}

// per-row int8 fake-quant of two [2048][2048] fp32 sources -> fp16 [2048][4096]
__global__ __launch_bounds__(256) void quant_rows(
    const float* __restrict__ s0, const float* __restrict__ s1,
    _Float16* __restrict__ dst)
{
  const int t = blockIdx.x, y = blockIdx.y;
  const float* src = (y ? s1 : s0) + (long long)t * 2048;
  const int tid = threadIdx.x, lane = tid & 63, wave = tid >> 6;
  __shared__ float rbuf[4];
  const v4f a = *(const v4f*)(src + tid * 4);
  const v4f b = *(const v4f*)(src + 1024 + tid * 4);
  float m = 0.f;
#pragma unroll
  for (int k = 0; k < 4; ++k)
    m = fmaxf(m, fmaxf(fabsf(a[k]), fabsf(b[k])));
  for (int o = 1; o < 64; o <<= 1) m = fmaxf(m, __shfl_xor(m, o, 64));
  if (lane == 0) rbuf[wave] = m;
  __syncthreads();
  m = fmaxf(fmaxf(rbuf[0], rbuf[1]), fmaxf(rbuf[2], rbuf[3]));
  const float scale = 127.f / fmaxf(m, 1e-5f);
  const float inv = 1.f / scale;
  _Float16* d = dst + (long long)t * 4096 + (long long)y * 2048 + tid * 4;
  v4h qa, qb;
#pragma unroll
  for (int k = 0; k < 4; ++k) {
    qa[k] = (_Float16)(fminf(fmaxf(rintf(a[k] * scale), -128.f), 127.f) * inv);
    qb[k] = (_Float16)(fminf(fmaxf(rintf(b[k] * scale), -128.f), 127.f) * inv);
  }
  *(v4h*)d = qa;
  *(v4h*)(d + 1024) = qb;
}

// Build concatenated complex weight matrices (fp16)
__global__ __launch_bounds__(256) void wprep(
    const float* __restrict__ Wq_r, const float* __restrict__ Wq_i,
    const float* __restrict__ Wk_r, const float* __restrict__ Wk_i,
    const float* __restrict__ Wv_r, const float* __restrict__ Wv_i,
    const float* __restrict__ Wo_r, const float* __restrict__ Wo_i,
    _Float16* __restrict__ Bqkv, _Float16* __restrict__ Bo)
{
  const float* Ws[8] = {Wq_r, Wq_i, Wk_r, Wk_i, Wv_r, Wv_i, Wo_r, Wo_i};
  const int i = blockIdx.x * 256 + threadIdx.x;
  const int w = i >> 18;
  const int rem = i & 262143;
  const int j = rem >> 7;
  const int cb = (rem & 127) * 16;
  const float* src = Ws[w] + (long long)j * 2048 + cb;
  _Float16* Bp = (w < 6) ? (Bqkv + (long long)(w >> 1) * 4096 * 4096) : Bo;
  const int isI = w & 1;
  _Float16* d1 = Bp + (long long)j * 4096 + (isI ? 2048 + cb : cb);
  _Float16* d2 = Bp + (long long)(2048 + j) * 4096 + (isI ? cb : 2048 + cb);
  const float sg2 = isI ? 1.f : -1.f;
#pragma unroll
  for (int q = 0; q < 4; ++q) {
    const v4f v = *(const v4f*)(src + q * 4);
    v4h o1, o2;
#pragma unroll
    for (int k = 0; k < 4; ++k) {
      o1[k] = (_Float16)v[k];
      o2[k] = (_Float16)(v[k] * sg2);
    }
    *(v4h*)(d1 + q * 4) = o1;
    *(v4h*)(d2 + q * 4) = o2;
  }
}

// cos/sin table [T][128] float2, bf16-rounded
__global__ __launch_bounds__(256) void trig_kernel(
    const int* __restrict__ pos, float* __restrict__ cs)
{
  const int t = blockIdx.x * 2 + (threadIdx.x >> 7);
  const int d = threadIdx.x & 127;
  const float invf = (float)pow(10000.0, -(double)d / 128.0);
  const float fr = (float)pos[t] * invf;
  const double fd = (double)fr;
  cs[((long long)t * 128 + d) * 2]     = bf16_rt((float)cos(fd));
  cs[((long long)t * 128 + d) * 2 + 1] = bf16_rt((float)sin(fd));
}

// vectorized RoPE: Yq [T][8192] (qr|qi|kr|ki) -> qc/kc [NH][T][256] fp16
__global__ __launch_bounds__(256) void rope_kernel(
    const _Float16* __restrict__ Yq, const float* __restrict__ cs,
    _Float16* __restrict__ qc, _Float16* __restrict__ kc)
{
  const int idx = blockIdx.x * 256 + threadIdx.x;
  const int d0 = (idx & 15) * 8;
  const int h  = (idx >> 4) & 15;
  const int t  = idx >> 8;
  const _Float16* y = Yq + (long long)t * 8192 + h * 128 + d0;
  const v8h qr8 = *(const v8h*)(y);
  const v8h qi8 = *(const v8h*)(y + 2048);
  const v8h kr8 = *(const v8h*)(y + 4096);
  const v8h ki8 = *(const v8h*)(y + 6144);
  const float* cp = cs + ((long long)t * 128 + d0) * 2;
  v8h qro, qio, kro, kio;
#pragma unroll
  for (int u = 0; u < 8; ++u) {
    const float c = cp[u * 2], s = cp[u * 2 + 1];
    const float qr = (float)qr8[u], qi = (float)qi8[u];
    const float kr = (float)kr8[u], ki = (float)ki8[u];
    qro[u] = (_Float16)(qr * c - qi * s);
    qio[u] = (_Float16)(qi * c + qr * s);
    kro[u] = (_Float16)(kr * c - ki * s);
    kio[u] = (_Float16)(ki * c + kr * s);
  }
  _Float16* qo = qc + ((long long)h * 2048 + t) * 256 + d0;
  _Float16* ko = kc + ((long long)h * 2048 + t) * 256 + d0;
  *(v8h*)qo = qro; *(v8h*)(qo + 128) = qio;
  *(v8h*)ko = kro; *(v8h*)(ko + 128) = kio;
}

// Fused causal flash attention v2 — R7 structure (KBLK=128), 4 blocks/CU.
// One block = 64 Q-rows of one head, 4 waves as 2(m)x2(n: 64-col halves),
// K-tile 128, D=256 (r|i concat). K/V direct from global (L2-resident),
// 2 __syncthreads per stage. R12: launch_bounds (256,4) packs 4 independent
// blocks/CU (all 512 blocks resident) — pure TLP, structure unchanged.
__global__ __launch_bounds__(256, 4) void flash_attn(
    const _Float16* __restrict__ qc, const _Float16* __restrict__ kc,
    const _Float16* __restrict__ vt, float* __restrict__ attn)
{
  __shared__ __align__(16) _Float16 Ps[64 * 136];  // 128 cols, pad ->136
  __shared__ float pmax[2][64];
  __shared__ float psum[2][64];

  const int h  = blockIdx.y;
  // load-balance remap: pair small-qt with large-qt across heads
  const int qt = ((h >> 3) & 1) ? (31 - (int)blockIdx.x) : (int)blockIdx.x;
  const int q0 = qt * 64;
  const int tid = threadIdx.x, lane = tid & 63, wave = tid >> 6;
  const int mi = wave >> 1, ni = wave & 1;
  const int quad = lane >> 4, l15 = lane & 15;

  const _Float16* qh = qc + (long long)h * 2048 * 256;
  const _Float16* kh = kc + (long long)h * 2048 * 256;
  const _Float16* vh = vt + (long long)h * 256 * 2048;

  // Q fragments in registers, pre-scaled by log2(e)/16 (exp2-domain softmax)
  const _Float16 scl = (_Float16)0.09016844f;
  v8h qf[2][8];
#pragma unroll
  for (int mt = 0; mt < 2; ++mt) {
    const int t = q0 + mi * 32 + mt * 16 + l15;
#pragma unroll
    for (int ks = 0; ks < 8; ++ks) {
      v8h q = *(const v8h*)(qh + (long long)t * 256 + ks * 32 + quad * 8);
#pragma unroll
      for (int u = 0; u < 8; ++u) q[u] *= scl;
      qf[mt][ks] = q;
    }
  }

  float mrow[2][4], lrow[2][4];
  v4f acc_o[2][8];
#pragma unroll
  for (int mt = 0; mt < 2; ++mt)
#pragma unroll
    for (int r = 0; r < 4; ++r) { mrow[mt][r] = -1e30f; lrow[mt][r] = 0.f; }
#pragma unroll
  for (int mt = 0; mt < 2; ++mt)
#pragma unroll
    for (int nt = 0; nt < 8; ++nt) acc_o[mt][nt] = (v4f){0.f, 0.f, 0.f, 0.f};

  const int nst = (qt >> 1) + 1;
  for (int st = 0; st < nst; ++st) {
    const int s0 = st * 128;
    const bool diag = (st == nst - 1);

    // wave-uniform liveness of each 16-col jn tile (cols fully above diag?)
    bool live[4];
#pragma unroll
    for (int jn = 0; jn < 4; ++jn)
      live[jn] = !diag || (s0 + ni * 64 + jn * 16 <= q0 + 63);

    // S half = Q @ K[128 cols; this wave's 64-col half]^T, K direct from L2
    v4f sa[2][4] = {};
#pragma unroll
    for (int ks = 0; ks < 8; ++ks) {
      v8h bk[4];
#pragma unroll
      for (int jn = 0; jn < 4; ++jn)
        if (live[jn])
          bk[jn] = *(const v8h*)(kh + (long long)(s0 + ni * 64 + jn * 16 + l15) * 256
                                 + ks * 32 + quad * 8);
#pragma unroll
      for (int mt = 0; mt < 2; ++mt)
#pragma unroll
        for (int jn = 0; jn < 4; ++jn)
          if (live[jn])
            sa[mt][jn] = __builtin_amdgcn_mfma_f32_16x16x32_f16(qf[mt][ks], bk[jn], sa[mt][jn], 0, 0, 0);
    }

    float pm[2][4];
#pragma unroll
    for (int mt = 0; mt < 2; ++mt)
#pragma unroll
      for (int r = 0; r < 4; ++r) pm[mt][r] = -1e30f;
#pragma unroll
    for (int mt = 0; mt < 2; ++mt)
#pragma unroll
      for (int jn = 0; jn < 4; ++jn)
#pragma unroll
        for (int r = 0; r < 4; ++r) {
          float v = sa[mt][jn][r];          // already log2-scaled
          if (diag) {
            const int rl = q0 + mi * 32 + mt * 16 + quad * 4 + r;
            const int cl = s0 + ni * 64 + jn * 16 + l15;
            if (cl > rl) v = -1e30f;
          }
          sa[mt][jn][r] = v;
          pm[mt][r] = fmaxf(pm[mt][r], v);
        }
#pragma unroll
    for (int o = 1; o < 16; o <<= 1)
#pragma unroll
      for (int mt = 0; mt < 2; ++mt)
#pragma unroll
        for (int r = 0; r < 4; ++r)
          pm[mt][r] = fmaxf(pm[mt][r], __shfl_xor(pm[mt][r], o, 64));
    if (l15 == 0) {
#pragma unroll
      for (int mt = 0; mt < 2; ++mt)
#pragma unroll
        for (int r = 0; r < 4; ++r)
          pmax[ni][mi * 32 + mt * 16 + quad * 4 + r] = pm[mt][r];
    }
    __syncthreads();   // B1: pmax visible

    float al[2][4], ps[2][4];
#pragma unroll
    for (int mt = 0; mt < 2; ++mt)
#pragma unroll
      for (int r = 0; r < 4; ++r) {
        const int row = mi * 32 + mt * 16 + quad * 4 + r;
        const float mn = fmaxf(mrow[mt][r], fmaxf(pmax[0][row], pmax[1][row]));
        al[mt][r] = __builtin_amdgcn_exp2f(mrow[mt][r] - mn);
        mrow[mt][r] = mn;
        ps[mt][r] = 0.f;
      }
#pragma unroll
    for (int mt = 0; mt < 2; ++mt)
#pragma unroll
      for (int jn = 0; jn < 4; ++jn)
#pragma unroll
        for (int r = 0; r < 4; ++r) {
          const float e = __builtin_amdgcn_exp2f(sa[mt][jn][r] - mrow[mt][r]);
          ps[mt][r] += e;
          Ps[(mi * 32 + mt * 16 + quad * 4 + r) * 136 + ni * 64 + jn * 16 + l15] = (_Float16)e;
        }
#pragma unroll
    for (int o = 1; o < 16; o <<= 1)
#pragma unroll
      for (int mt = 0; mt < 2; ++mt)
#pragma unroll
        for (int r = 0; r < 4; ++r)
          ps[mt][r] += __shfl_xor(ps[mt][r], o, 64);
    if (l15 == 0) {
#pragma unroll
      for (int mt = 0; mt < 2; ++mt)
#pragma unroll
        for (int r = 0; r < 4; ++r)
          psum[ni][mi * 32 + mt * 16 + quad * 4 + r] = ps[mt][r];
    }
    __syncthreads();   // B2: Ps + psum visible

#pragma unroll
    for (int mt = 0; mt < 2; ++mt)
#pragma unroll
      for (int r = 0; r < 4; ++r) {
        const int row = mi * 32 + mt * 16 + quad * 4 + r;
        lrow[mt][r] = lrow[mt][r] * al[mt][r] + psum[0][row] + psum[1][row];
      }
#pragma unroll
    for (int mt = 0; mt < 2; ++mt)
#pragma unroll
      for (int nt = 0; nt < 8; ++nt)
#pragma unroll
        for (int r = 0; r < 4; ++r)
          acc_o[mt][nt][r] *= al[mt][r];

    // O += P @ V over 128 cols; P from LDS, V direct from global (L2-hot).
    // Slabs fully above the diagonal carry P==0 -> skip (wave-uniform).
#pragma unroll
    for (int kc2 = 0; kc2 < 4; ++kc2) {
      if (diag && (s0 + kc2 * 32 > q0 + 63)) continue;
      v8h pa[2];
#pragma unroll
      for (int mt = 0; mt < 2; ++mt) {
        const int row = mi * 32 + mt * 16 + l15;
        pa[mt] = *(const v8h*)(Ps + row * 136 + kc2 * 32 + quad * 8);
      }
#pragma unroll
      for (int nt = 0; nt < 8; ++nt) {
        const v8h vb = *(const v8h*)(vh + (long long)(ni * 128 + nt * 16 + l15) * 2048
                                     + s0 + kc2 * 32 + quad * 8);
#pragma unroll
        for (int mt = 0; mt < 2; ++mt)
          acc_o[mt][nt] = __builtin_amdgcn_mfma_f32_16x16x32_f16(pa[mt], vb, acc_o[mt][nt], 0, 0, 0);
      }
    }
    // no tail barrier: next-stage Ps/pmax writes are gated by B1/B2 above
  }

  // epilogue: O/l -> attn (r-part at 0, i-part at +2048*2048 floats)
#pragma unroll
  for (int mt = 0; mt < 2; ++mt) {
    float inv[4];
#pragma unroll
    for (int r = 0; r < 4; ++r) inv[r] = 1.f / lrow[mt][r];
#pragma unroll
    for (int nt = 0; nt < 8; ++nt) {
      const int d = ni * 128 + nt * 16 + l15;
      float* dst = attn + ((d < 128) ? 0ll : (2048ll * 2048)) + (h * 128 + (d & 127));
#pragma unroll
      for (int r = 0; r < 4; ++r) {
        const int t = q0 + mi * 32 + mt * 16 + quad * 4 + r;
        dst[(long long)t * 2048] = acc_o[mt][nt][r] * inv[r];
      }
    }
  }
}

extern "C" void kernel_launch(void* const* d_in, const int* in_sizes, int n_in,
                              void* d_out, int out_size, void* d_ws, size_t ws_size,
                              hipStream_t stream) {
  const float* hr   = (const float*)d_in[0];
  const float* hi   = (const float*)d_in[1];
  const int*   pos  = (const int*)d_in[2];
  const float* Wq_r = (const float*)d_in[3];
  const float* Wq_i = (const float*)d_in[4];
  const float* Wk_r = (const float*)d_in[5];
  const float* Wk_i = (const float*)d_in[6];
  const float* Wv_r = (const float*)d_in[7];
  const float* Wv_i = (const float*)d_in[8];
  const float* Wo_r = (const float*)d_in[9];
  const float* Wo_i = (const float*)d_in[10];

  char* ws = (char*)d_ws;
  _Float16* Bqkv = (_Float16*)(ws);                    // 96MB
  float*    attn = (float*)   (ws);                    // 32MB (alias, post-QKV)
  float*    cs   = (float*)   (ws + (32ll  << 20));    // 2MB  (alias, post-QKV)
  _Float16* Bo   = (_Float16*)(ws + (96ll  << 20));    // 32MB
  _Float16* Ac   = (_Float16*)(ws + (128ll << 20));    // 16MB
  _Float16* Yq   = (_Float16*)(ws + (144ll << 20));    // 32MB (q,k only)
  _Float16* qc   = (_Float16*)(ws + (176ll << 20));    // 16MB
  _Float16* kc   = (_Float16*)(ws + (192ll << 20));    // 16MB
  _Float16* vt   = (_Float16*)(ws + (208ll << 20));    // 16MB

  quant_rows<<<dim3(2048, 2), 256, 0, stream>>>(hr, hi, Ac);
  wprep<<<8192, 256, 0, stream>>>(Wq_r, Wq_i, Wk_r, Wk_i, Wv_r, Wv_i, Wo_r, Wo_i, Bqkv, Bo);
  // fused QKV: [qr|qi](2048x4096) @ Bqkv(12288x4096)^T -> Yq (q,k) + vt (v)
  gemm_qkv256<<<512, 512, 0, stream>>>(Ac, Bqkv, Yq, vt);
  trig_kernel<<<1024, 256, 0, stream>>>(pos, cs);
  rope_kernel<<<2048, 256, 0, stream>>>(Yq, cs, qc, kc);
  flash_attn<<<dim3(32, 16), 256, 0, stream>>>(qc, kc, vt, attn);
  quant_rows<<<dim3(2048, 2), 256, 0, stream>>>(attn, attn + 2048ll * 2048, Ac);
  // output projection -> d_out = [yr (T*H) | yi (T*H)] fp32
  gemm_out256<<<256, 512, 0, stream>>>(Ac, Bo, (float*)d_out);
}

// Round 9
// 896.542 us; speedup vs baseline: 1.2369x; 1.2369x over previous
//
#include <hip/hip_runtime.h>

// ComplexNetAttention on gfx950.
// Pipeline: int8-fakequant -> fused complex QKV GEMM (fp16 MFMA, NT, K=4096;
//   8-phase counted-vmcnt schedule, 256x192 tile) -> cos/sin table +
//   vectorized RoPE -> fused flash attention v2 (KBLK=128, R13: 3 blocks/CU) ->
//   fakequant -> out GEMM (256x128 8-phase counted-vmcnt).
//
// R13: R8's (256,4) forced VGPR 116->64 and spilled (WRITE_SIZE 33->517MB,
// flash 628us). Same TLP experiment, spill-free: __launch_bounds__(256,3)
// -> VGPR cap ~170 (kernel needs 116, no spill), 3 independent blocks/CU
// (12 waves/CU, +50% TLP over R7). Everything else byte-identical to R7
// (686us best).

typedef float v4f __attribute__((ext_vector_type(4)));
typedef _Float16 v8h __attribute__((ext_vector_type(8)));
typedef _Float16 v4h __attribute__((ext_vector_type(4)));

typedef const __attribute__((address_space(1))) void glob_void;
typedef __attribute__((address_space(3))) void lds_void;

__device__ __forceinline__ void gload16(const _Float16* gp, _Float16* lp) {
  __builtin_amdgcn_global_load_lds((glob_void*)gp, (lds_void*)lp, 16, 0, 0);
}

// bf16 round-trip (RNE) in fp32 — matches reference's bf16 cos/sin cache.
__device__ __forceinline__ float bf16_rt(float f) {
  union { float f; unsigned u; } a; a.f = f;
  unsigned r = (a.u + 0x7fffu + ((a.u >> 16) & 1u)) & 0xffff0000u;
  union { unsigned u; float f; } b; b.u = r;
  return b.f;
}

#define SBAR()  __builtin_amdgcn_sched_barrier(0)
#define WBAR()  __builtin_amdgcn_s_barrier()
#define LGKM0() asm volatile("s_waitcnt lgkmcnt(0)" ::: "memory")

// ---------------------------------------------------------------------------
// QKV GEMM: C[2048][12288] = A[2048][4096] @ B[12288][4096]^T, fp16, fp32 acc.
// Tile 256x192, BK=64, 512 thr (8 waves 2m x 4n), wave-tile 128x48.
// 8-phase counted-vmcnt schedule (T3+T4), XOR chunk swizzle (0-conflict),
// s_setprio around MFMA clusters (T5), bijective XCD chunking (T1).
// ---------------------------------------------------------------------------
__global__ __launch_bounds__(512, 2) void gemm_qkv256(
    const _Float16* __restrict__ A, const _Float16* __restrict__ B,
    _Float16* __restrict__ Yq, _Float16* __restrict__ vt)
{
  const int p = blockIdx.x;            // 0..511, XCD = p & 7 (round-robin)
  const int xcd = p & 7, s = p >> 3;   // s: 0..63 within chunk
  const int mt = s & 7, ntl = s >> 3;
  const int nt = xcd * 8 + ntl;        // 0..63
  const int m0 = mt << 8;              // *256
  const int n0 = nt * 192;

  __shared__ __align__(16) _Float16 lds[57344];  // 2 bufs x (16384 A + 12288 B)

  const int tid = threadIdx.x, lane = tid & 63, wave = tid >> 6;
  const int quad = lane >> 4, l15 = lane & 15;
  const int wm = wave >> 2, wn = wave & 3;       // 2 x 4 waves

  // staging constants: for gload j covering LDS halfs [j*4096 + tid*8):
  // r = (j&1)*128 + tid>>2, pc = tid&3, lc = pc ^ ((r>>1)&3)
  const int rr = tid >> 2;                                   // 0..127
  const int lc8 = (((tid & 3) ^ ((tid >> 3) & 3)) << 3);     // logical chunk*8
  const _Float16* gA = A + (long long)(m0 + rr) * 4096 + lc8;
  // B tile = 24KB = 3 gloads; gload 1 crosses the ks0/ks1 subtile boundary.
  const _Float16* gBj[3];
#pragma unroll
  for (int j = 0; j < 3; ++j) {
    const int ks = (j == 2) || (j == 1 && tid >= 256);
    const int r = j * 128 + (tid >> 2) - ks * 192;
    gBj[j] = B + (long long)(n0 + r) * 4096 + ks * 32 + lc8;
  }

  // read constants: phys chunk = quad ^ ((l15>>1)&3), constant per lane
  const int co = ((quad ^ ((l15 >> 1) & 3)) << 3);
  const int aBase = (wm * 128 + l15) * 32 + co;
  const int bBase = (wn * 48 + l15) * 32 + co;

  v4f acc[8][3] = {};

  // prologue: stage tile 0 -> buf 0 in canonical order a0,a1,b0,b1,a2,a3,b2
  {
    _Float16* sd = lds + tid * 8;
    gload16(gA, sd);
    gload16(gA + 524288, sd + 4096);          // 128*4096
    gload16(gBj[0], sd + 16384);
    gload16(gBj[1], sd + 20480);
    gload16(gA + 32, sd + 8192);
    gload16(gA + 524288 + 32, sd + 12288);
    gload16(gBj[2], sd + 24576);
  }
  asm volatile("s_waitcnt vmcnt(3)" ::: "memory");  // first-4 of tile 0 done
  WBAR();

  for (int t = 0; t < 64; ++t) {
    const _Float16* As = lds + (t & 1) * 28672;
    const _Float16* Bs = As + 16384;
    _Float16* sd = lds + ((t & 1) ^ 1) * 28672 + tid * 8;
    const int k1 = (t + 1) << 6;
    const bool stg = (t < 63);

    v8h bf[3], af[4];

    // ===== P0: ds bf(ks0)+af(mh0,ks0); stage a0,a1(t+1) =====
    af[0] = *(const v8h*)&As[aBase];
    af[1] = *(const v8h*)&As[aBase + 512];
    af[2] = *(const v8h*)&As[aBase + 1024];
    af[3] = *(const v8h*)&As[aBase + 1536];
    bf[0] = *(const v8h*)&Bs[bBase];
    bf[1] = *(const v8h*)&Bs[bBase + 512];
    bf[2] = *(const v8h*)&Bs[bBase + 1024];
    if (stg) { gload16(gA + k1, sd); gload16(gA + k1 + 524288, sd + 4096); }
    SBAR(); WBAR(); LGKM0(); SBAR();
    __builtin_amdgcn_s_setprio(1);
#pragma unroll
    for (int i = 0; i < 4; ++i)
#pragma unroll
      for (int nf = 0; nf < 3; ++nf)
        acc[i][nf] = __builtin_amdgcn_mfma_f32_16x16x32_f16(af[i], bf[nf], acc[i][nf], 0, 0, 0);
    __builtin_amdgcn_s_setprio(0);
    WBAR();

    // ===== P1: ds af(mh1,ks0); stage b0,b1(t+1); vmcnt(4) =====
    af[0] = *(const v8h*)&As[aBase + 2048];
    af[1] = *(const v8h*)&As[aBase + 2560];
    af[2] = *(const v8h*)&As[aBase + 3072];
    af[3] = *(const v8h*)&As[aBase + 3584];
    if (stg) { gload16(gBj[0] + k1, sd + 16384); gload16(gBj[1] + k1, sd + 20480); }
    SBAR(); WBAR(); LGKM0(); SBAR();
    __builtin_amdgcn_s_setprio(1);
#pragma unroll
    for (int i = 0; i < 4; ++i)
#pragma unroll
      for (int nf = 0; nf < 3; ++nf)
        acc[4 + i][nf] = __builtin_amdgcn_mfma_f32_16x16x32_f16(af[i], bf[nf], acc[4 + i][nf], 0, 0, 0);
    __builtin_amdgcn_s_setprio(0);
    if (stg) asm volatile("s_waitcnt vmcnt(4)" ::: "memory");
    else     asm volatile("s_waitcnt vmcnt(0)" ::: "memory");
    WBAR();

    // ===== P2: ds bf(ks1)+af(mh0,ks1); stage a2,a3(t+1) =====
    bf[0] = *(const v8h*)&Bs[bBase + 6144];
    bf[1] = *(const v8h*)&Bs[bBase + 6656];
    bf[2] = *(const v8h*)&Bs[bBase + 7168];
    af[0] = *(const v8h*)&As[aBase + 8192];
    af[1] = *(const v8h*)&As[aBase + 8704];
    af[2] = *(const v8h*)&As[aBase + 9216];
    af[3] = *(const v8h*)&As[aBase + 9728];
    if (stg) { gload16(gA + k1 + 32, sd + 8192); gload16(gA + k1 + 524288 + 32, sd + 12288); }
    SBAR(); WBAR(); LGKM0(); SBAR();
    __builtin_amdgcn_s_setprio(1);
#pragma unroll
    for (int i = 0; i < 4; ++i)
#pragma unroll
      for (int nf = 0; nf < 3; ++nf)
        acc[i][nf] = __builtin_amdgcn_mfma_f32_16x16x32_f16(af[i], bf[nf], acc[i][nf], 0, 0, 0);
    __builtin_amdgcn_s_setprio(0);
    WBAR();

    // ===== P3: ds af(mh1,ks1); stage b2(t+1); vmcnt(3) =====
    af[0] = *(const v8h*)&As[aBase + 10240];
    af[1] = *(const v8h*)&As[aBase + 10752];
    af[2] = *(const v8h*)&As[aBase + 11264];
    af[3] = *(const v8h*)&As[aBase + 11776];
    if (stg) gload16(gBj[2] + k1, sd + 24576);
    SBAR(); WBAR(); LGKM0(); SBAR();
    __builtin_amdgcn_s_setprio(1);
#pragma unroll
    for (int i = 0; i < 4; ++i)
#pragma unroll
      for (int nf = 0; nf < 3; ++nf)
        acc[4 + i][nf] = __builtin_amdgcn_mfma_f32_16x16x32_f16(af[i], bf[nf], acc[4 + i][nf], 0, 0, 0);
    __builtin_amdgcn_s_setprio(0);
    if (stg) asm volatile("s_waitcnt vmcnt(3)" ::: "memory");
    WBAR();
  }

  // epilogue: C/D layout col=lane&15, row=quad*4+reg (m89/m91-verified)
#pragma unroll
  for (int mf = 0; mf < 8; ++mf) {
#pragma unroll
    for (int nf = 0; nf < 3; ++nf) {
      const int col = n0 + wn * 48 + nf * 16 + l15;
      const int row0 = m0 + wm * 128 + mf * 16 + quad * 4;   // multiple of 4
      if (col >= 8192) {
        // v projection -> vt[NH][256][2048], packed 4 rows per store
        const int c = col - 8192;
        const int hh = (c & 2047) >> 7;
        const int dcol = (c < 2048) ? (c & 127) : (128 + (c & 127));
        v4h pk;
#pragma unroll
        for (int r = 0; r < 4; ++r) pk[r] = (_Float16)acc[mf][nf][r];
        *(v4h*)(vt + ((long long)(hh * 256 + dcol)) * 2048 + row0) = pk;
      } else {
#pragma unroll
        for (int r = 0; r < 4; ++r)
          Yq[(long long)(row0 + r) * 8192 + col] = (_Float16)acc[mf][nf][r];
      }
    }
  }
}

// ---------------------------------------------------------------------------
// Out GEMM: O[2048][4096] = A[2048][4096] @ B[4096][4096]^T, fp32 out,
// split cols [yr|yi] into concatenated halves of d_out.
// 256x128 tile, BK=64, 8-phase counted-vmcnt (proven R10). Grid 256 = 1/CU.
// ---------------------------------------------------------------------------
__global__ __launch_bounds__(512, 2) void gemm_out256(
    const _Float16* __restrict__ A, const _Float16* __restrict__ B,
    float* __restrict__ O)
{
  const int p = blockIdx.x;            // 0..255
  const int xcd = p & 7, s = p >> 3;   // s: 0..31
  const int mt = s & 7, ntl = s >> 3;  // 8 m-tiles, 4 n-tiles per XCD
  const int nt = xcd * 4 + ntl;        // 0..31
  const int m0 = mt << 8, n0 = nt << 7;

  __shared__ __align__(16) _Float16 lds[49152];  // 2 bufs x (16384 A + 8192 B)

  const int tid = threadIdx.x, lane = tid & 63, wave = tid >> 6;
  const int quad = lane >> 4, l15 = lane & 15;
  const int wm = wave >> 2, wn = wave & 3;       // 2 x 4 waves

  const int rr = tid >> 2;                                   // 0..127
  const int lc8 = (((tid & 3) ^ ((tid >> 3) & 3)) << 3);     // logical chunk*8
  const _Float16* gA = A + (long long)(m0 + rr) * 4096 + lc8;
  const _Float16* gB = B + (long long)(n0 + rr) * 4096 + lc8;

  const int co = ((quad ^ ((l15 >> 1) & 3)) << 3);
  const int aBase = (wm * 128 + l15) * 32 + co;
  const int bBase = (wn * 32 + l15) * 32 + co;

  v4f acc[8][2] = {};

  // prologue: stage tile 0 -> buf 0, first-half trio first
  {
    _Float16* sd = lds + tid * 8;
    gload16(gA, sd);                        // a0: rows 0-127, ks0
    gload16(gA + 524288, sd + 4096);        // a1: rows 128-255, ks0
    gload16(gB, sd + 16384);                // b0: ks0
    gload16(gA + 32, sd + 8192);            // a2: rows 0-127, ks1
    gload16(gA + 524288 + 32, sd + 12288);  // a3: rows 128-255, ks1
    gload16(gB + 32, sd + 20480);           // b1: ks1
  }
  asm volatile("s_waitcnt vmcnt(3)" ::: "memory");  // first trio of tile 0
  WBAR();

  for (int t = 0; t < 64; ++t) {
    const _Float16* As = lds + (t & 1) * 24576;
    const _Float16* Bs = As + 16384;
    _Float16* sd = lds + ((t & 1) ^ 1) * 24576 + tid * 8;
    const int k1 = (t + 1) << 6;
    const bool stg = (t < 63);

    v8h bf[2], af[4];

    // ===== P0: ds af(mh0,ks0)+bf(ks0); stage a0,a1(t+1) =====
    af[0] = *(const v8h*)&As[aBase];
    af[1] = *(const v8h*)&As[aBase + 512];
    af[2] = *(const v8h*)&As[aBase + 1024];
    af[3] = *(const v8h*)&As[aBase + 1536];
    bf[0] = *(const v8h*)&Bs[bBase];
    bf[1] = *(const v8h*)&Bs[bBase + 512];
    if (stg) { gload16(gA + k1, sd); gload16(gA + k1 + 524288, sd + 4096); }
    SBAR(); WBAR(); LGKM0(); SBAR();
    __builtin_amdgcn_s_setprio(1);
#pragma unroll
    for (int i = 0; i < 4; ++i)
#pragma unroll
      for (int nf = 0; nf < 2; ++nf)
        acc[i][nf] = __builtin_amdgcn_mfma_f32_16x16x32_f16(af[i], bf[nf], acc[i][nf], 0, 0, 0);
    __builtin_amdgcn_s_setprio(0);
    WBAR();

    // ===== P1: ds af(mh1,ks0); stage b0(t+1); vmcnt(3) =====
    af[0] = *(const v8h*)&As[aBase + 2048];
    af[1] = *(const v8h*)&As[aBase + 2560];
    af[2] = *(const v8h*)&As[aBase + 3072];
    af[3] = *(const v8h*)&As[aBase + 3584];
    if (stg) gload16(gB + k1, sd + 16384);
    SBAR(); WBAR(); LGKM0(); SBAR();
    __builtin_amdgcn_s_setprio(1);
#pragma unroll
    for (int i = 0; i < 4; ++i)
#pragma unroll
      for (int nf = 0; nf < 2; ++nf)
        acc[4 + i][nf] = __builtin_amdgcn_mfma_f32_16x16x32_f16(af[i], bf[nf], acc[4 + i][nf], 0, 0, 0);
    __builtin_amdgcn_s_setprio(0);
    // retire this tile's ks1 trio {a2,a3,b1}; leave t+1's first trio in flight
    if (stg) asm volatile("s_waitcnt vmcnt(3)" ::: "memory");
    else     asm volatile("s_waitcnt vmcnt(0)" ::: "memory");
    WBAR();

    // ===== P2: ds bf(ks1)+af(mh0,ks1); stage a2,a3(t+1) =====
    bf[0] = *(const v8h*)&Bs[bBase + 4096];
    bf[1] = *(const v8h*)&Bs[bBase + 4608];
    af[0] = *(const v8h*)&As[aBase + 8192];
    af[1] = *(const v8h*)&As[aBase + 8704];
    af[2] = *(const v8h*)&As[aBase + 9216];
    af[3] = *(const v8h*)&As[aBase + 9728];
    if (stg) { gload16(gA + k1 + 32, sd + 8192); gload16(gA + k1 + 524288 + 32, sd + 12288); }
    SBAR(); WBAR(); LGKM0(); SBAR();
    __builtin_amdgcn_s_setprio(1);
#pragma unroll
    for (int i = 0; i < 4; ++i)
#pragma unroll
      for (int nf = 0; nf < 2; ++nf)
        acc[i][nf] = __builtin_amdgcn_mfma_f32_16x16x32_f16(af[i], bf[nf], acc[i][nf], 0, 0, 0);
    __builtin_amdgcn_s_setprio(0);
    WBAR();

    // ===== P3: ds af(mh1,ks1); stage b1(t+1); vmcnt(3) =====
    af[0] = *(const v8h*)&As[aBase + 10240];
    af[1] = *(const v8h*)&As[aBase + 10752];
    af[2] = *(const v8h*)&As[aBase + 11264];
    af[3] = *(const v8h*)&As[aBase + 11776];
    if (stg) gload16(gB + k1 + 32, sd + 20480);
    SBAR(); WBAR(); LGKM0(); SBAR();
    __builtin_amdgcn_s_setprio(1);
#pragma unroll
    for (int i = 0; i < 4; ++i)
#pragma unroll
      for (int nf = 0; nf < 2; ++nf)
        acc[4 + i][nf] = __builtin_amdgcn_mfma_f32_16x16x32_f16(af[i], bf[nf], acc[4 + i][nf], 0, 0, 0);
    __builtin_amdgcn_s_setprio(0);
    // retire t+1's first trio {a0,a1,b0}; leave its ks1 trio in flight
    if (stg) asm volatile("s_waitcnt vmcnt(3)" ::: "memory");
    WBAR();
  }

  // epilogue: fp32, split cols [yr|yi] into concatenated halves of d_out
#pragma unroll
  for (int mf = 0; mf < 8; ++mf) {
#pragma unroll
    for (int nf = 0; nf < 2; ++nf) {
      const int col = n0 + wn * 32 + nf * 16 + l15;
      const int row0 = m0 + wm * 128 + mf * 16 + quad * 4;
#pragma unroll
      for (int r = 0; r < 4; ++r) {
        const int row = row0 + r;
        const float v = acc[mf][nf][r];
        if (col < 2048) O[(long long)row * 2048 + col] = v;
        else O[2048ll * 2048 + (long long)row * 2048 + (col - 2048)] = v;
      }
    }
  }
}

// per-row int8 fake-quant of two [2048][2048] fp32 sources -> fp16 [2048][4096]
__global__ __launch_bounds__(256) void quant_rows(
    const float* __restrict__ s0, const float* __restrict__ s1,
    _Float16* __restrict__ dst)
{
  const int t = blockIdx.x, y = blockIdx.y;
  const float* src = (y ? s1 : s0) + (long long)t * 2048;
  const int tid = threadIdx.x, lane = tid & 63, wave = tid >> 6;
  __shared__ float rbuf[4];
  const v4f a = *(const v4f*)(src + tid * 4);
  const v4f b = *(const v4f*)(src + 1024 + tid * 4);
  float m = 0.f;
#pragma unroll
  for (int k = 0; k < 4; ++k)
    m = fmaxf(m, fmaxf(fabsf(a[k]), fabsf(b[k])));
  for (int o = 1; o < 64; o <<= 1) m = fmaxf(m, __shfl_xor(m, o, 64));
  if (lane == 0) rbuf[wave] = m;
  __syncthreads();
  m = fmaxf(fmaxf(rbuf[0], rbuf[1]), fmaxf(rbuf[2], rbuf[3]));
  const float scale = 127.f / fmaxf(m, 1e-5f);
  const float inv = 1.f / scale;
  _Float16* d = dst + (long long)t * 4096 + (long long)y * 2048 + tid * 4;
  v4h qa, qb;
#pragma unroll
  for (int k = 0; k < 4; ++k) {
    qa[k] = (_Float16)(fminf(fmaxf(rintf(a[k] * scale), -128.f), 127.f) * inv);
    qb[k] = (_Float16)(fminf(fmaxf(rintf(b[k] * scale), -128.f), 127.f) * inv);
  }
  *(v4h*)d = qa;
  *(v4h*)(d + 1024) = qb;
}

// Build concatenated complex weight matrices (fp16)
__global__ __launch_bounds__(256) void wprep(
    const float* __restrict__ Wq_r, const float* __restrict__ Wq_i,
    const float* __restrict__ Wk_r, const float* __restrict__ Wk_i,
    const float* __restrict__ Wv_r, const float* __restrict__ Wv_i,
    const float* __restrict__ Wo_r, const float* __restrict__ Wo_i,
    _Float16* __restrict__ Bqkv, _Float16* __restrict__ Bo)
{
  const float* Ws[8] = {Wq_r, Wq_i, Wk_r, Wk_i, Wv_r, Wv_i, Wo_r, Wo_i};
  const int i = blockIdx.x * 256 + threadIdx.x;
  const int w = i >> 18;
  const int rem = i & 262143;
  const int j = rem >> 7;
  const int cb = (rem & 127) * 16;
  const float* src = Ws[w] + (long long)j * 2048 + cb;
  _Float16* Bp = (w < 6) ? (Bqkv + (long long)(w >> 1) * 4096 * 4096) : Bo;
  const int isI = w & 1;
  _Float16* d1 = Bp + (long long)j * 4096 + (isI ? 2048 + cb : cb);
  _Float16* d2 = Bp + (long long)(2048 + j) * 4096 + (isI ? cb : 2048 + cb);
  const float sg2 = isI ? 1.f : -1.f;
#pragma unroll
  for (int q = 0; q < 4; ++q) {
    const v4f v = *(const v4f*)(src + q * 4);
    v4h o1, o2;
#pragma unroll
    for (int k = 0; k < 4; ++k) {
      o1[k] = (_Float16)v[k];
      o2[k] = (_Float16)(v[k] * sg2);
    }
    *(v4h*)(d1 + q * 4) = o1;
    *(v4h*)(d2 + q * 4) = o2;
  }
}

// cos/sin table [T][128] float2, bf16-rounded
__global__ __launch_bounds__(256) void trig_kernel(
    const int* __restrict__ pos, float* __restrict__ cs)
{
  const int t = blockIdx.x * 2 + (threadIdx.x >> 7);
  const int d = threadIdx.x & 127;
  const float invf = (float)pow(10000.0, -(double)d / 128.0);
  const float fr = (float)pos[t] * invf;
  const double fd = (double)fr;
  cs[((long long)t * 128 + d) * 2]     = bf16_rt((float)cos(fd));
  cs[((long long)t * 128 + d) * 2 + 1] = bf16_rt((float)sin(fd));
}

// vectorized RoPE: Yq [T][8192] (qr|qi|kr|ki) -> qc/kc [NH][T][256] fp16
__global__ __launch_bounds__(256) void rope_kernel(
    const _Float16* __restrict__ Yq, const float* __restrict__ cs,
    _Float16* __restrict__ qc, _Float16* __restrict__ kc)
{
  const int idx = blockIdx.x * 256 + threadIdx.x;
  const int d0 = (idx & 15) * 8;
  const int h  = (idx >> 4) & 15;
  const int t  = idx >> 8;
  const _Float16* y = Yq + (long long)t * 8192 + h * 128 + d0;
  const v8h qr8 = *(const v8h*)(y);
  const v8h qi8 = *(const v8h*)(y + 2048);
  const v8h kr8 = *(const v8h*)(y + 4096);
  const v8h ki8 = *(const v8h*)(y + 6144);
  const float* cp = cs + ((long long)t * 128 + d0) * 2;
  v8h qro, qio, kro, kio;
#pragma unroll
  for (int u = 0; u < 8; ++u) {
    const float c = cp[u * 2], s = cp[u * 2 + 1];
    const float qr = (float)qr8[u], qi = (float)qi8[u];
    const float kr = (float)kr8[u], ki = (float)ki8[u];
    qro[u] = (_Float16)(qr * c - qi * s);
    qio[u] = (_Float16)(qi * c + qr * s);
    kro[u] = (_Float16)(kr * c - ki * s);
    kio[u] = (_Float16)(ki * c + kr * s);
  }
  _Float16* qo = qc + ((long long)h * 2048 + t) * 256 + d0;
  _Float16* ko = kc + ((long long)h * 2048 + t) * 256 + d0;
  *(v8h*)qo = qro; *(v8h*)(qo + 128) = qio;
  *(v8h*)ko = kro; *(v8h*)(ko + 128) = kio;
}

// Fused causal flash attention v2 — R7 structure (KBLK=128), 3 blocks/CU.
// One block = 64 Q-rows of one head, 4 waves as 2(m)x2(n: 64-col halves),
// K-tile 128, D=256 (r|i concat). K/V direct from global (L2-resident),
// 2 __syncthreads per stage. R13: launch_bounds (256,3) -> VGPR cap ~170
// (no spill at 116), 3 independent blocks/CU = 12 waves/CU.
__global__ __launch_bounds__(256, 3) void flash_attn(
    const _Float16* __restrict__ qc, const _Float16* __restrict__ kc,
    const _Float16* __restrict__ vt, float* __restrict__ attn)
{
  __shared__ __align__(16) _Float16 Ps[64 * 136];  // 128 cols, pad ->136
  __shared__ float pmax[2][64];
  __shared__ float psum[2][64];

  const int h  = blockIdx.y;
  // load-balance remap: pair small-qt with large-qt across heads
  const int qt = ((h >> 3) & 1) ? (31 - (int)blockIdx.x) : (int)blockIdx.x;
  const int q0 = qt * 64;
  const int tid = threadIdx.x, lane = tid & 63, wave = tid >> 6;
  const int mi = wave >> 1, ni = wave & 1;
  const int quad = lane >> 4, l15 = lane & 15;

  const _Float16* qh = qc + (long long)h * 2048 * 256;
  const _Float16* kh = kc + (long long)h * 2048 * 256;
  const _Float16* vh = vt + (long long)h * 256 * 2048;

  // Q fragments in registers, pre-scaled by log2(e)/16 (exp2-domain softmax)
  const _Float16 scl = (_Float16)0.09016844f;
  v8h qf[2][8];
#pragma unroll
  for (int mt = 0; mt < 2; ++mt) {
    const int t = q0 + mi * 32 + mt * 16 + l15;
#pragma unroll
    for (int ks = 0; ks < 8; ++ks) {
      v8h q = *(const v8h*)(qh + (long long)t * 256 + ks * 32 + quad * 8);
#pragma unroll
      for (int u = 0; u < 8; ++u) q[u] *= scl;
      qf[mt][ks] = q;
    }
  }

  float mrow[2][4], lrow[2][4];
  v4f acc_o[2][8];
#pragma unroll
  for (int mt = 0; mt < 2; ++mt)
#pragma unroll
    for (int r = 0; r < 4; ++r) { mrow[mt][r] = -1e30f; lrow[mt][r] = 0.f; }
#pragma unroll
  for (int mt = 0; mt < 2; ++mt)
#pragma unroll
    for (int nt = 0; nt < 8; ++nt) acc_o[mt][nt] = (v4f){0.f, 0.f, 0.f, 0.f};

  const int nst = (qt >> 1) + 1;
  for (int st = 0; st < nst; ++st) {
    const int s0 = st * 128;
    const bool diag = (st == nst - 1);

    // wave-uniform liveness of each 16-col jn tile (cols fully above diag?)
    bool live[4];
#pragma unroll
    for (int jn = 0; jn < 4; ++jn)
      live[jn] = !diag || (s0 + ni * 64 + jn * 16 <= q0 + 63);

    // S half = Q @ K[128 cols; this wave's 64-col half]^T, K direct from L2
    v4f sa[2][4] = {};
#pragma unroll
    for (int ks = 0; ks < 8; ++ks) {
      v8h bk[4];
#pragma unroll
      for (int jn = 0; jn < 4; ++jn)
        if (live[jn])
          bk[jn] = *(const v8h*)(kh + (long long)(s0 + ni * 64 + jn * 16 + l15) * 256
                                 + ks * 32 + quad * 8);
#pragma unroll
      for (int mt = 0; mt < 2; ++mt)
#pragma unroll
        for (int jn = 0; jn < 4; ++jn)
          if (live[jn])
            sa[mt][jn] = __builtin_amdgcn_mfma_f32_16x16x32_f16(qf[mt][ks], bk[jn], sa[mt][jn], 0, 0, 0);
    }

    float pm[2][4];
#pragma unroll
    for (int mt = 0; mt < 2; ++mt)
#pragma unroll
      for (int r = 0; r < 4; ++r) pm[mt][r] = -1e30f;
#pragma unroll
    for (int mt = 0; mt < 2; ++mt)
#pragma unroll
      for (int jn = 0; jn < 4; ++jn)
#pragma unroll
        for (int r = 0; r < 4; ++r) {
          float v = sa[mt][jn][r];          // already log2-scaled
          if (diag) {
            const int rl = q0 + mi * 32 + mt * 16 + quad * 4 + r;
            const int cl = s0 + ni * 64 + jn * 16 + l15;
            if (cl > rl) v = -1e30f;
          }
          sa[mt][jn][r] = v;
          pm[mt][r] = fmaxf(pm[mt][r], v);
        }
#pragma unroll
    for (int o = 1; o < 16; o <<= 1)
#pragma unroll
      for (int mt = 0; mt < 2; ++mt)
#pragma unroll
        for (int r = 0; r < 4; ++r)
          pm[mt][r] = fmaxf(pm[mt][r], __shfl_xor(pm[mt][r], o, 64));
    if (l15 == 0) {
#pragma unroll
      for (int mt = 0; mt < 2; ++mt)
#pragma unroll
        for (int r = 0; r < 4; ++r)
          pmax[ni][mi * 32 + mt * 16 + quad * 4 + r] = pm[mt][r];
    }
    __syncthreads();   // B1: pmax visible

    float al[2][4], ps[2][4];
#pragma unroll
    for (int mt = 0; mt < 2; ++mt)
#pragma unroll
      for (int r = 0; r < 4; ++r) {
        const int row = mi * 32 + mt * 16 + quad * 4 + r;
        const float mn = fmaxf(mrow[mt][r], fmaxf(pmax[0][row], pmax[1][row]));
        al[mt][r] = __builtin_amdgcn_exp2f(mrow[mt][r] - mn);
        mrow[mt][r] = mn;
        ps[mt][r] = 0.f;
      }
#pragma unroll
    for (int mt = 0; mt < 2; ++mt)
#pragma unroll
      for (int jn = 0; jn < 4; ++jn)
#pragma unroll
        for (int r = 0; r < 4; ++r) {
          const float e = __builtin_amdgcn_exp2f(sa[mt][jn][r] - mrow[mt][r]);
          ps[mt][r] += e;
          Ps[(mi * 32 + mt * 16 + quad * 4 + r) * 136 + ni * 64 + jn * 16 + l15] = (_Float16)e;
        }
#pragma unroll
    for (int o = 1; o < 16; o <<= 1)
#pragma unroll
      for (int mt = 0; mt < 2; ++mt)
#pragma unroll
        for (int r = 0; r < 4; ++r)
          ps[mt][r] += __shfl_xor(ps[mt][r], o, 64);
    if (l15 == 0) {
#pragma unroll
      for (int mt = 0; mt < 2; ++mt)
#pragma unroll
        for (int r = 0; r < 4; ++r)
          psum[ni][mi * 32 + mt * 16 + quad * 4 + r] = ps[mt][r];
    }
    __syncthreads();   // B2: Ps + psum visible

#pragma unroll
    for (int mt = 0; mt < 2; ++mt)
#pragma unroll
      for (int r = 0; r < 4; ++r) {
        const int row = mi * 32 + mt * 16 + quad * 4 + r;
        lrow[mt][r] = lrow[mt][r] * al[mt][r] + psum[0][row] + psum[1][row];
      }
#pragma unroll
    for (int mt = 0; mt < 2; ++mt)
#pragma unroll
      for (int nt = 0; nt < 8; ++nt)
#pragma unroll
        for (int r = 0; r < 4; ++r)
          acc_o[mt][nt][r] *= al[mt][r];

    // O += P @ V over 128 cols; P from LDS, V direct from global (L2-hot).
    // Slabs fully above the diagonal carry P==0 -> skip (wave-uniform).
#pragma unroll
    for (int kc2 = 0; kc2 < 4; ++kc2) {
      if (diag && (s0 + kc2 * 32 > q0 + 63)) continue;
      v8h pa[2];
#pragma unroll
      for (int mt = 0; mt < 2; ++mt) {
        const int row = mi * 32 + mt * 16 + l15;
        pa[mt] = *(const v8h*)(Ps + row * 136 + kc2 * 32 + quad * 8);
      }
#pragma unroll
      for (int nt = 0; nt < 8; ++nt) {
        const v8h vb = *(const v8h*)(vh + (long long)(ni * 128 + nt * 16 + l15) * 2048
                                     + s0 + kc2 * 32 + quad * 8);
#pragma unroll
        for (int mt = 0; mt < 2; ++mt)
          acc_o[mt][nt] = __builtin_amdgcn_mfma_f32_16x16x32_f16(pa[mt], vb, acc_o[mt][nt], 0, 0, 0);
      }
    }
    // no tail barrier: next-stage Ps/pmax writes are gated by B1/B2 above
  }

  // epilogue: O/l -> attn (r-part at 0, i-part at +2048*2048 floats)
#pragma unroll
  for (int mt = 0; mt < 2; ++mt) {
    float inv[4];
#pragma unroll
    for (int r = 0; r < 4; ++r) inv[r] = 1.f / lrow[mt][r];
#pragma unroll
    for (int nt = 0; nt < 8; ++nt) {
      const int d = ni * 128 + nt * 16 + l15;
      float* dst = attn + ((d < 128) ? 0ll : (2048ll * 2048)) + (h * 128 + (d & 127));
#pragma unroll
      for (int r = 0; r < 4; ++r) {
        const int t = q0 + mi * 32 + mt * 16 + quad * 4 + r;
        dst[(long long)t * 2048] = acc_o[mt][nt][r] * inv[r];
      }
    }
  }
}

extern "C" void kernel_launch(void* const* d_in, const int* in_sizes, int n_in,
                              void* d_out, int out_size, void* d_ws, size_t ws_size,
                              hipStream_t stream) {
  const float* hr   = (const float*)d_in[0];
  const float* hi   = (const float*)d_in[1];
  const int*   pos  = (const int*)d_in[2];
  const float* Wq_r = (const float*)d_in[3];
  const float* Wq_i = (const float*)d_in[4];
  const float* Wk_r = (const float*)d_in[5];
  const float* Wk_i = (const float*)d_in[6];
  const float* Wv_r = (const float*)d_in[7];
  const float* Wv_i = (const float*)d_in[8];
  const float* Wo_r = (const float*)d_in[9];
  const float* Wo_i = (const float*)d_in[10];

  char* ws = (char*)d_ws;
  _Float16* Bqkv = (_Float16*)(ws);                    // 96MB
  float*    attn = (float*)   (ws);                    // 32MB (alias, post-QKV)
  float*    cs   = (float*)   (ws + (32ll  << 20));    // 2MB  (alias, post-QKV)
  _Float16* Bo   = (_Float16*)(ws + (96ll  << 20));    // 32MB
  _Float16* Ac   = (_Float16*)(ws + (128ll << 20));    // 16MB
  _Float16* Yq   = (_Float16*)(ws + (144ll << 20));    // 32MB (q,k only)
  _Float16* qc   = (_Float16*)(ws + (176ll << 20));    // 16MB
  _Float16* kc   = (_Float16*)(ws + (192ll << 20));    // 16MB
  _Float16* vt   = (_Float16*)(ws + (208ll << 20));    // 16MB

  quant_rows<<<dim3(2048, 2), 256, 0, stream>>>(hr, hi, Ac);
  wprep<<<8192, 256, 0, stream>>>(Wq_r, Wq_i, Wk_r, Wk_i, Wv_r, Wv_i, Wo_r, Wo_i, Bqkv, Bo);
  // fused QKV: [qr|qi](2048x4096) @ Bqkv(12288x4096)^T -> Yq (q,k) + vt (v)
  gemm_qkv256<<<512, 512, 0, stream>>>(Ac, Bqkv, Yq, vt);
  trig_kernel<<<1024, 256, 0, stream>>>(pos, cs);
  rope_kernel<<<2048, 256, 0, stream>>>(Yq, cs, qc, kc);
  flash_attn<<<dim3(32, 16), 256, 0, stream>>>(qc, kc, vt, attn);
  quant_rows<<<dim3(2048, 2), 256, 0, stream>>>(attn, attn + 2048ll * 2048, Ac);
  // output projection -> d_out = [yr (T*H) | yi (T*H)] fp32
  gemm_out256<<<256, 512, 0, stream>>>(Ac, Bo, (float*)d_out);
}

// Round 10
// 815.363 us; speedup vs baseline: 1.3601x; 1.0996x over previous
//
#include <hip/hip_runtime.h>

// ComplexNetAttention on gfx950.
// Pipeline: int8-fakequant -> fused complex QKV GEMM (fp16 MFMA, NT, K=4096;
//   8-phase counted-vmcnt schedule, 256x192 tile) -> cos/sin table +
//   vectorized RoPE -> fused flash attention v2 (R14: KBLK=192) ->
//   fakequant -> out GEMM (256x128 8-phase counted-vmcnt).
//
// R14: R8/R9 spills proved launch-bounds TLP is ill-posed (grid 512 = 2
// blocks/CU max resident regardless). Flash reverted to R7's exact sync
// structure + launch_bounds(256,2) (686us best), with ONE change on the
// only axis that ever helped (R11: KBLK 64->128 = -16us): KBLK=192.
// Stage count 272->176 per head (~-35%), amortizing the per-stage fixed
// overhead (F~13ns, W~11ns/64col fit from R2/R3). VGPR ~200-220 < 256 cap
// at 2 waves/EU -> no spill; LDS 26.6KB x2 = 53KB fits.

typedef float v4f __attribute__((ext_vector_type(4)));
typedef _Float16 v8h __attribute__((ext_vector_type(8)));
typedef _Float16 v4h __attribute__((ext_vector_type(4)));

typedef const __attribute__((address_space(1))) void glob_void;
typedef __attribute__((address_space(3))) void lds_void;

__device__ __forceinline__ void gload16(const _Float16* gp, _Float16* lp) {
  __builtin_amdgcn_global_load_lds((glob_void*)gp, (lds_void*)lp, 16, 0, 0);
}

// bf16 round-trip (RNE) in fp32 — matches reference's bf16 cos/sin cache.
__device__ __forceinline__ float bf16_rt(float f) {
  union { float f; unsigned u; } a; a.f = f;
  unsigned r = (a.u + 0x7fffu + ((a.u >> 16) & 1u)) & 0xffff0000u;
  union { unsigned u; float f; } b; b.u = r;
  return b.f;
}

#define SBAR()  __builtin_amdgcn_sched_barrier(0)
#define WBAR()  __builtin_amdgcn_s_barrier()
#define LGKM0() asm volatile("s_waitcnt lgkmcnt(0)" ::: "memory")

// ---------------------------------------------------------------------------
// QKV GEMM: C[2048][12288] = A[2048][4096] @ B[12288][4096]^T, fp16, fp32 acc.
// Tile 256x192, BK=64, 512 thr (8 waves 2m x 4n), wave-tile 128x48.
// 8-phase counted-vmcnt schedule (T3+T4), XOR chunk swizzle (0-conflict),
// s_setprio around MFMA clusters (T5), bijective XCD chunking (T1).
// ---------------------------------------------------------------------------
__global__ __launch_bounds__(512, 2) void gemm_qkv256(
    const _Float16* __restrict__ A, const _Float16* __restrict__ B,
    _Float16* __restrict__ Yq, _Float16* __restrict__ vt)
{
  const int p = blockIdx.x;            // 0..511, XCD = p & 7 (round-robin)
  const int xcd = p & 7, s = p >> 3;   // s: 0..63 within chunk
  const int mt = s & 7, ntl = s >> 3;
  const int nt = xcd * 8 + ntl;        // 0..63
  const int m0 = mt << 8;              // *256
  const int n0 = nt * 192;

  __shared__ __align__(16) _Float16 lds[57344];  // 2 bufs x (16384 A + 12288 B)

  const int tid = threadIdx.x, lane = tid & 63, wave = tid >> 6;
  const int quad = lane >> 4, l15 = lane & 15;
  const int wm = wave >> 2, wn = wave & 3;       // 2 x 4 waves

  // staging constants: for gload j covering LDS halfs [j*4096 + tid*8):
  // r = (j&1)*128 + tid>>2, pc = tid&3, lc = pc ^ ((r>>1)&3)
  const int rr = tid >> 2;                                   // 0..127
  const int lc8 = (((tid & 3) ^ ((tid >> 3) & 3)) << 3);     // logical chunk*8
  const _Float16* gA = A + (long long)(m0 + rr) * 4096 + lc8;
  // B tile = 24KB = 3 gloads; gload 1 crosses the ks0/ks1 subtile boundary.
  const _Float16* gBj[3];
#pragma unroll
  for (int j = 0; j < 3; ++j) {
    const int ks = (j == 2) || (j == 1 && tid >= 256);
    const int r = j * 128 + (tid >> 2) - ks * 192;
    gBj[j] = B + (long long)(n0 + r) * 4096 + ks * 32 + lc8;
  }

  // read constants: phys chunk = quad ^ ((l15>>1)&3), constant per lane
  const int co = ((quad ^ ((l15 >> 1) & 3)) << 3);
  const int aBase = (wm * 128 + l15) * 32 + co;
  const int bBase = (wn * 48 + l15) * 32 + co;

  v4f acc[8][3] = {};

  // prologue: stage tile 0 -> buf 0 in canonical order a0,a1,b0,b1,a2,a3,b2
  {
    _Float16* sd = lds + tid * 8;
    gload16(gA, sd);
    gload16(gA + 524288, sd + 4096);          // 128*4096
    gload16(gBj[0], sd + 16384);
    gload16(gBj[1], sd + 20480);
    gload16(gA + 32, sd + 8192);
    gload16(gA + 524288 + 32, sd + 12288);
    gload16(gBj[2], sd + 24576);
  }
  asm volatile("s_waitcnt vmcnt(3)" ::: "memory");  // first-4 of tile 0 done
  WBAR();

  for (int t = 0; t < 64; ++t) {
    const _Float16* As = lds + (t & 1) * 28672;
    const _Float16* Bs = As + 16384;
    _Float16* sd = lds + ((t & 1) ^ 1) * 28672 + tid * 8;
    const int k1 = (t + 1) << 6;
    const bool stg = (t < 63);

    v8h bf[3], af[4];

    // ===== P0: ds bf(ks0)+af(mh0,ks0); stage a0,a1(t+1) =====
    af[0] = *(const v8h*)&As[aBase];
    af[1] = *(const v8h*)&As[aBase + 512];
    af[2] = *(const v8h*)&As[aBase + 1024];
    af[3] = *(const v8h*)&As[aBase + 1536];
    bf[0] = *(const v8h*)&Bs[bBase];
    bf[1] = *(const v8h*)&Bs[bBase + 512];
    bf[2] = *(const v8h*)&Bs[bBase + 1024];
    if (stg) { gload16(gA + k1, sd); gload16(gA + k1 + 524288, sd + 4096); }
    SBAR(); WBAR(); LGKM0(); SBAR();
    __builtin_amdgcn_s_setprio(1);
#pragma unroll
    for (int i = 0; i < 4; ++i)
#pragma unroll
      for (int nf = 0; nf < 3; ++nf)
        acc[i][nf] = __builtin_amdgcn_mfma_f32_16x16x32_f16(af[i], bf[nf], acc[i][nf], 0, 0, 0);
    __builtin_amdgcn_s_setprio(0);
    WBAR();

    // ===== P1: ds af(mh1,ks0); stage b0,b1(t+1); vmcnt(4) =====
    af[0] = *(const v8h*)&As[aBase + 2048];
    af[1] = *(const v8h*)&As[aBase + 2560];
    af[2] = *(const v8h*)&As[aBase + 3072];
    af[3] = *(const v8h*)&As[aBase + 3584];
    if (stg) { gload16(gBj[0] + k1, sd + 16384); gload16(gBj[1] + k1, sd + 20480); }
    SBAR(); WBAR(); LGKM0(); SBAR();
    __builtin_amdgcn_s_setprio(1);
#pragma unroll
    for (int i = 0; i < 4; ++i)
#pragma unroll
      for (int nf = 0; nf < 3; ++nf)
        acc[4 + i][nf] = __builtin_amdgcn_mfma_f32_16x16x32_f16(af[i], bf[nf], acc[4 + i][nf], 0, 0, 0);
    __builtin_amdgcn_s_setprio(0);
    if (stg) asm volatile("s_waitcnt vmcnt(4)" ::: "memory");
    else     asm volatile("s_waitcnt vmcnt(0)" ::: "memory");
    WBAR();

    // ===== P2: ds bf(ks1)+af(mh0,ks1); stage a2,a3(t+1) =====
    bf[0] = *(const v8h*)&Bs[bBase + 6144];
    bf[1] = *(const v8h*)&Bs[bBase + 6656];
    bf[2] = *(const v8h*)&Bs[bBase + 7168];
    af[0] = *(const v8h*)&As[aBase + 8192];
    af[1] = *(const v8h*)&As[aBase + 8704];
    af[2] = *(const v8h*)&As[aBase + 9216];
    af[3] = *(const v8h*)&As[aBase + 9728];
    if (stg) { gload16(gA + k1 + 32, sd + 8192); gload16(gA + k1 + 524288 + 32, sd + 12288); }
    SBAR(); WBAR(); LGKM0(); SBAR();
    __builtin_amdgcn_s_setprio(1);
#pragma unroll
    for (int i = 0; i < 4; ++i)
#pragma unroll
      for (int nf = 0; nf < 3; ++nf)
        acc[i][nf] = __builtin_amdgcn_mfma_f32_16x16x32_f16(af[i], bf[nf], acc[i][nf], 0, 0, 0);
    __builtin_amdgcn_s_setprio(0);
    WBAR();

    // ===== P3: ds af(mh1,ks1); stage b2(t+1); vmcnt(3) =====
    af[0] = *(const v8h*)&As[aBase + 10240];
    af[1] = *(const v8h*)&As[aBase + 10752];
    af[2] = *(const v8h*)&As[aBase + 11264];
    af[3] = *(const v8h*)&As[aBase + 11776];
    if (stg) gload16(gBj[2] + k1, sd + 24576);
    SBAR(); WBAR(); LGKM0(); SBAR();
    __builtin_amdgcn_s_setprio(1);
#pragma unroll
    for (int i = 0; i < 4; ++i)
#pragma unroll
      for (int nf = 0; nf < 3; ++nf)
        acc[4 + i][nf] = __builtin_amdgcn_mfma_f32_16x16x32_f16(af[i], bf[nf], acc[4 + i][nf], 0, 0, 0);
    __builtin_amdgcn_s_setprio(0);
    if (stg) asm volatile("s_waitcnt vmcnt(3)" ::: "memory");
    WBAR();
  }

  // epilogue: C/D layout col=lane&15, row=quad*4+reg (m89/m91-verified)
#pragma unroll
  for (int mf = 0; mf < 8; ++mf) {
#pragma unroll
    for (int nf = 0; nf < 3; ++nf) {
      const int col = n0 + wn * 48 + nf * 16 + l15;
      const int row0 = m0 + wm * 128 + mf * 16 + quad * 4;   // multiple of 4
      if (col >= 8192) {
        // v projection -> vt[NH][256][2048], packed 4 rows per store
        const int c = col - 8192;
        const int hh = (c & 2047) >> 7;
        const int dcol = (c < 2048) ? (c & 127) : (128 + (c & 127));
        v4h pk;
#pragma unroll
        for (int r = 0; r < 4; ++r) pk[r] = (_Float16)acc[mf][nf][r];
        *(v4h*)(vt + ((long long)(hh * 256 + dcol)) * 2048 + row0) = pk;
      } else {
#pragma unroll
        for (int r = 0; r < 4; ++r)
          Yq[(long long)(row0 + r) * 8192 + col] = (_Float16)acc[mf][nf][r];
      }
    }
  }
}

// ---------------------------------------------------------------------------
// Out GEMM: O[2048][4096] = A[2048][4096] @ B[4096][4096]^T, fp32 out,
// split cols [yr|yi] into concatenated halves of d_out.
// 256x128 tile, BK=64, 8-phase counted-vmcnt (proven R10). Grid 256 = 1/CU.
// ---------------------------------------------------------------------------
__global__ __launch_bounds__(512, 2) void gemm_out256(
    const _Float16* __restrict__ A, const _Float16* __restrict__ B,
    float* __restrict__ O)
{
  const int p = blockIdx.x;            // 0..255
  const int xcd = p & 7, s = p >> 3;   // s: 0..31
  const int mt = s & 7, ntl = s >> 3;  // 8 m-tiles, 4 n-tiles per XCD
  const int nt = xcd * 4 + ntl;        // 0..31
  const int m0 = mt << 8, n0 = nt << 7;

  __shared__ __align__(16) _Float16 lds[49152];  // 2 bufs x (16384 A + 8192 B)

  const int tid = threadIdx.x, lane = tid & 63, wave = tid >> 6;
  const int quad = lane >> 4, l15 = lane & 15;
  const int wm = wave >> 2, wn = wave & 3;       // 2 x 4 waves

  const int rr = tid >> 2;                                   // 0..127
  const int lc8 = (((tid & 3) ^ ((tid >> 3) & 3)) << 3);     // logical chunk*8
  const _Float16* gA = A + (long long)(m0 + rr) * 4096 + lc8;
  const _Float16* gB = B + (long long)(n0 + rr) * 4096 + lc8;

  const int co = ((quad ^ ((l15 >> 1) & 3)) << 3);
  const int aBase = (wm * 128 + l15) * 32 + co;
  const int bBase = (wn * 32 + l15) * 32 + co;

  v4f acc[8][2] = {};

  // prologue: stage tile 0 -> buf 0, first-half trio first
  {
    _Float16* sd = lds + tid * 8;
    gload16(gA, sd);                        // a0: rows 0-127, ks0
    gload16(gA + 524288, sd + 4096);        // a1: rows 128-255, ks0
    gload16(gB, sd + 16384);                // b0: ks0
    gload16(gA + 32, sd + 8192);            // a2: rows 0-127, ks1
    gload16(gA + 524288 + 32, sd + 12288);  // a3: rows 128-255, ks1
    gload16(gB + 32, sd + 20480);           // b1: ks1
  }
  asm volatile("s_waitcnt vmcnt(3)" ::: "memory");  // first trio of tile 0
  WBAR();

  for (int t = 0; t < 64; ++t) {
    const _Float16* As = lds + (t & 1) * 24576;
    const _Float16* Bs = As + 16384;
    _Float16* sd = lds + ((t & 1) ^ 1) * 24576 + tid * 8;
    const int k1 = (t + 1) << 6;
    const bool stg = (t < 63);

    v8h bf[2], af[4];

    // ===== P0: ds af(mh0,ks0)+bf(ks0); stage a0,a1(t+1) =====
    af[0] = *(const v8h*)&As[aBase];
    af[1] = *(const v8h*)&As[aBase + 512];
    af[2] = *(const v8h*)&As[aBase + 1024];
    af[3] = *(const v8h*)&As[aBase + 1536];
    bf[0] = *(const v8h*)&Bs[bBase];
    bf[1] = *(const v8h*)&Bs[bBase + 512];
    if (stg) { gload16(gA + k1, sd); gload16(gA + k1 + 524288, sd + 4096); }
    SBAR(); WBAR(); LGKM0(); SBAR();
    __builtin_amdgcn_s_setprio(1);
#pragma unroll
    for (int i = 0; i < 4; ++i)
#pragma unroll
      for (int nf = 0; nf < 2; ++nf)
        acc[i][nf] = __builtin_amdgcn_mfma_f32_16x16x32_f16(af[i], bf[nf], acc[i][nf], 0, 0, 0);
    __builtin_amdgcn_s_setprio(0);
    WBAR();

    // ===== P1: ds af(mh1,ks0); stage b0(t+1); vmcnt(3) =====
    af[0] = *(const v8h*)&As[aBase + 2048];
    af[1] = *(const v8h*)&As[aBase + 2560];
    af[2] = *(const v8h*)&As[aBase + 3072];
    af[3] = *(const v8h*)&As[aBase + 3584];
    if (stg) gload16(gB + k1, sd + 16384);
    SBAR(); WBAR(); LGKM0(); SBAR();
    __builtin_amdgcn_s_setprio(1);
#pragma unroll
    for (int i = 0; i < 4; ++i)
#pragma unroll
      for (int nf = 0; nf < 2; ++nf)
        acc[4 + i][nf] = __builtin_amdgcn_mfma_f32_16x16x32_f16(af[i], bf[nf], acc[4 + i][nf], 0, 0, 0);
    __builtin_amdgcn_s_setprio(0);
    // retire this tile's ks1 trio {a2,a3,b1}; leave t+1's first trio in flight
    if (stg) asm volatile("s_waitcnt vmcnt(3)" ::: "memory");
    else     asm volatile("s_waitcnt vmcnt(0)" ::: "memory");
    WBAR();

    // ===== P2: ds bf(ks1)+af(mh0,ks1); stage a2,a3(t+1) =====
    bf[0] = *(const v8h*)&Bs[bBase + 4096];
    bf[1] = *(const v8h*)&Bs[bBase + 4608];
    af[0] = *(const v8h*)&As[aBase + 8192];
    af[1] = *(const v8h*)&As[aBase + 8704];
    af[2] = *(const v8h*)&As[aBase + 9216];
    af[3] = *(const v8h*)&As[aBase + 9728];
    if (stg) { gload16(gA + k1 + 32, sd + 8192); gload16(gA + k1 + 524288 + 32, sd + 12288); }
    SBAR(); WBAR(); LGKM0(); SBAR();
    __builtin_amdgcn_s_setprio(1);
#pragma unroll
    for (int i = 0; i < 4; ++i)
#pragma unroll
      for (int nf = 0; nf < 2; ++nf)
        acc[i][nf] = __builtin_amdgcn_mfma_f32_16x16x32_f16(af[i], bf[nf], acc[i][nf], 0, 0, 0);
    __builtin_amdgcn_s_setprio(0);
    WBAR();

    // ===== P3: ds af(mh1,ks1); stage b1(t+1); vmcnt(3) =====
    af[0] = *(const v8h*)&As[aBase + 10240];
    af[1] = *(const v8h*)&As[aBase + 10752];
    af[2] = *(const v8h*)&As[aBase + 11264];
    af[3] = *(const v8h*)&As[aBase + 11776];
    if (stg) gload16(gB + k1 + 32, sd + 20480);
    SBAR(); WBAR(); LGKM0(); SBAR();
    __builtin_amdgcn_s_setprio(1);
#pragma unroll
    for (int i = 0; i < 4; ++i)
#pragma unroll
      for (int nf = 0; nf < 2; ++nf)
        acc[4 + i][nf] = __builtin_amdgcn_mfma_f32_16x16x32_f16(af[i], bf[nf], acc[4 + i][nf], 0, 0, 0);
    __builtin_amdgcn_s_setprio(0);
    // retire t+1's first trio {a0,a1,b0}; leave its ks1 trio in flight
    if (stg) asm volatile("s_waitcnt vmcnt(3)" ::: "memory");
    WBAR();
  }

  // epilogue: fp32, split cols [yr|yi] into concatenated halves of d_out
#pragma unroll
  for (int mf = 0; mf < 8; ++mf) {
#pragma unroll
    for (int nf = 0; nf < 2; ++nf) {
      const int col = n0 + wn * 32 + nf * 16 + l15;
      const int row0 = m0 + wm * 128 + mf * 16 + quad * 4;
#pragma unroll
      for (int r = 0; r < 4; ++r) {
        const int row = row0 + r;
        const float v = acc[mf][nf][r];
        if (col < 2048) O[(long long)row * 2048 + col] = v;
        else O[2048ll * 2048 + (long long)row * 2048 + (col - 2048)] = v;
      }
    }
  }
}

// per-row int8 fake-quant of two [2048][2048] fp32 sources -> fp16 [2048][4096]
__global__ __launch_bounds__(256) void quant_rows(
    const float* __restrict__ s0, const float* __restrict__ s1,
    _Float16* __restrict__ dst)
{
  const int t = blockIdx.x, y = blockIdx.y;
  const float* src = (y ? s1 : s0) + (long long)t * 2048;
  const int tid = threadIdx.x, lane = tid & 63, wave = tid >> 6;
  __shared__ float rbuf[4];
  const v4f a = *(const v4f*)(src + tid * 4);
  const v4f b = *(const v4f*)(src + 1024 + tid * 4);
  float m = 0.f;
#pragma unroll
  for (int k = 0; k < 4; ++k)
    m = fmaxf(m, fmaxf(fabsf(a[k]), fabsf(b[k])));
  for (int o = 1; o < 64; o <<= 1) m = fmaxf(m, __shfl_xor(m, o, 64));
  if (lane == 0) rbuf[wave] = m;
  __syncthreads();
  m = fmaxf(fmaxf(rbuf[0], rbuf[1]), fmaxf(rbuf[2], rbuf[3]));
  const float scale = 127.f / fmaxf(m, 1e-5f);
  const float inv = 1.f / scale;
  _Float16* d = dst + (long long)t * 4096 + (long long)y * 2048 + tid * 4;
  v4h qa, qb;
#pragma unroll
  for (int k = 0; k < 4; ++k) {
    qa[k] = (_Float16)(fminf(fmaxf(rintf(a[k] * scale), -128.f), 127.f) * inv);
    qb[k] = (_Float16)(fminf(fmaxf(rintf(b[k] * scale), -128.f), 127.f) * inv);
  }
  *(v4h*)d = qa;
  *(v4h*)(d + 1024) = qb;
}

// Build concatenated complex weight matrices (fp16)
__global__ __launch_bounds__(256) void wprep(
    const float* __restrict__ Wq_r, const float* __restrict__ Wq_i,
    const float* __restrict__ Wk_r, const float* __restrict__ Wk_i,
    const float* __restrict__ Wv_r, const float* __restrict__ Wv_i,
    const float* __restrict__ Wo_r, const float* __restrict__ Wo_i,
    _Float16* __restrict__ Bqkv, _Float16* __restrict__ Bo)
{
  const float* Ws[8] = {Wq_r, Wq_i, Wk_r, Wk_i, Wv_r, Wv_i, Wo_r, Wo_i};
  const int i = blockIdx.x * 256 + threadIdx.x;
  const int w = i >> 18;
  const int rem = i & 262143;
  const int j = rem >> 7;
  const int cb = (rem & 127) * 16;
  const float* src = Ws[w] + (long long)j * 2048 + cb;
  _Float16* Bp = (w < 6) ? (Bqkv + (long long)(w >> 1) * 4096 * 4096) : Bo;
  const int isI = w & 1;
  _Float16* d1 = Bp + (long long)j * 4096 + (isI ? 2048 + cb : cb);
  _Float16* d2 = Bp + (long long)(2048 + j) * 4096 + (isI ? cb : 2048 + cb);
  const float sg2 = isI ? 1.f : -1.f;
#pragma unroll
  for (int q = 0; q < 4; ++q) {
    const v4f v = *(const v4f*)(src + q * 4);
    v4h o1, o2;
#pragma unroll
    for (int k = 0; k < 4; ++k) {
      o1[k] = (_Float16)v[k];
      o2[k] = (_Float16)(v[k] * sg2);
    }
    *(v4h*)(d1 + q * 4) = o1;
    *(v4h*)(d2 + q * 4) = o2;
  }
}

// cos/sin table [T][128] float2, bf16-rounded
__global__ __launch_bounds__(256) void trig_kernel(
    const int* __restrict__ pos, float* __restrict__ cs)
{
  const int t = blockIdx.x * 2 + (threadIdx.x >> 7);
  const int d = threadIdx.x & 127;
  const float invf = (float)pow(10000.0, -(double)d / 128.0);
  const float fr = (float)pos[t] * invf;
  const double fd = (double)fr;
  cs[((long long)t * 128 + d) * 2]     = bf16_rt((float)cos(fd));
  cs[((long long)t * 128 + d) * 2 + 1] = bf16_rt((float)sin(fd));
}

// vectorized RoPE: Yq [T][8192] (qr|qi|kr|ki) -> qc/kc [NH][T][256] fp16
__global__ __launch_bounds__(256) void rope_kernel(
    const _Float16* __restrict__ Yq, const float* __restrict__ cs,
    _Float16* __restrict__ qc, _Float16* __restrict__ kc)
{
  const int idx = blockIdx.x * 256 + threadIdx.x;
  const int d0 = (idx & 15) * 8;
  const int h  = (idx >> 4) & 15;
  const int t  = idx >> 8;
  const _Float16* y = Yq + (long long)t * 8192 + h * 128 + d0;
  const v8h qr8 = *(const v8h*)(y);
  const v8h qi8 = *(const v8h*)(y + 2048);
  const v8h kr8 = *(const v8h*)(y + 4096);
  const v8h ki8 = *(const v8h*)(y + 6144);
  const float* cp = cs + ((long long)t * 128 + d0) * 2;
  v8h qro, qio, kro, kio;
#pragma unroll
  for (int u = 0; u < 8; ++u) {
    const float c = cp[u * 2], s = cp[u * 2 + 1];
    const float qr = (float)qr8[u], qi = (float)qi8[u];
    const float kr = (float)kr8[u], ki = (float)ki8[u];
    qro[u] = (_Float16)(qr * c - qi * s);
    qio[u] = (_Float16)(qi * c + qr * s);
    kro[u] = (_Float16)(kr * c - ki * s);
    kio[u] = (_Float16)(ki * c + kr * s);
  }
  _Float16* qo = qc + ((long long)h * 2048 + t) * 256 + d0;
  _Float16* ko = kc + ((long long)h * 2048 + t) * 256 + d0;
  *(v8h*)qo = qro; *(v8h*)(qo + 128) = qio;
  *(v8h*)ko = kro; *(v8h*)(ko + 128) = kio;
}

// Fused causal flash attention v2 — R7 sync structure, KBLK=192 (R14).
// One block = 64 Q-rows of one head, 4 waves as 2(m)x2(n: 96-col halves),
// K-tile 192, D=256 (r|i concat). K/V direct from global (L2-resident),
// 2 __syncthreads per stage, launch_bounds(256,2) (R7-exact, no spill).
__global__ __launch_bounds__(256, 2) void flash_attn(
    const _Float16* __restrict__ qc, const _Float16* __restrict__ kc,
    const _Float16* __restrict__ vt, float* __restrict__ attn)
{
  __shared__ __align__(16) _Float16 Ps[64 * 200];  // 192 cols, pad ->200
  __shared__ float pmax[2][64];
  __shared__ float psum[2][64];

  const int h  = blockIdx.y;
  // load-balance remap: pair small-qt with large-qt across heads
  const int qt = ((h >> 3) & 1) ? (31 - (int)blockIdx.x) : (int)blockIdx.x;
  const int q0 = qt * 64;
  const int tid = threadIdx.x, lane = tid & 63, wave = tid >> 6;
  const int mi = wave >> 1, ni = wave & 1;
  const int quad = lane >> 4, l15 = lane & 15;

  const _Float16* qh = qc + (long long)h * 2048 * 256;
  const _Float16* kh = kc + (long long)h * 2048 * 256;
  const _Float16* vh = vt + (long long)h * 256 * 2048;

  // Q fragments in registers, pre-scaled by log2(e)/16 (exp2-domain softmax)
  const _Float16 scl = (_Float16)0.09016844f;
  v8h qf[2][8];
#pragma unroll
  for (int mt = 0; mt < 2; ++mt) {
    const int t = q0 + mi * 32 + mt * 16 + l15;
#pragma unroll
    for (int ks = 0; ks < 8; ++ks) {
      v8h q = *(const v8h*)(qh + (long long)t * 256 + ks * 32 + quad * 8);
#pragma unroll
      for (int u = 0; u < 8; ++u) q[u] *= scl;
      qf[mt][ks] = q;
    }
  }

  float mrow[2][4], lrow[2][4];
  v4f acc_o[2][8];
#pragma unroll
  for (int mt = 0; mt < 2; ++mt)
#pragma unroll
    for (int r = 0; r < 4; ++r) { mrow[mt][r] = -1e30f; lrow[mt][r] = 0.f; }
#pragma unroll
  for (int mt = 0; mt < 2; ++mt)
#pragma unroll
    for (int nt = 0; nt < 8; ++nt) acc_o[mt][nt] = (v4f){0.f, 0.f, 0.f, 0.f};

  const int nst = (qt + 3) / 3;   // ceil((qt+1)*64 / 192)
  for (int st = 0; st < nst; ++st) {
    const int s0 = st * 192;
    const bool diag = (st == nst - 1);

    // wave-uniform liveness of each 16-col jn tile (cols fully above diag?)
    bool live[6];
#pragma unroll
    for (int jn = 0; jn < 6; ++jn)
      live[jn] = !diag || (s0 + ni * 96 + jn * 16 <= q0 + 63);

    // S half = Q @ K[192 cols; this wave's 96-col half]^T, K direct from L2
    v4f sa[2][6] = {};
#pragma unroll
    for (int ks = 0; ks < 8; ++ks) {
      v8h bk[6];
#pragma unroll
      for (int jn = 0; jn < 6; ++jn)
        if (live[jn])
          bk[jn] = *(const v8h*)(kh + (long long)(s0 + ni * 96 + jn * 16 + l15) * 256
                                 + ks * 32 + quad * 8);
#pragma unroll
      for (int mt = 0; mt < 2; ++mt)
#pragma unroll
        for (int jn = 0; jn < 6; ++jn)
          if (live[jn])
            sa[mt][jn] = __builtin_amdgcn_mfma_f32_16x16x32_f16(qf[mt][ks], bk[jn], sa[mt][jn], 0, 0, 0);
    }

    float pm[2][4];
#pragma unroll
    for (int mt = 0; mt < 2; ++mt)
#pragma unroll
      for (int r = 0; r < 4; ++r) pm[mt][r] = -1e30f;
#pragma unroll
    for (int mt = 0; mt < 2; ++mt)
#pragma unroll
      for (int jn = 0; jn < 6; ++jn)
#pragma unroll
        for (int r = 0; r < 4; ++r) {
          float v = live[jn] ? sa[mt][jn][r] : -1e30f;   // already log2-scaled
          if (diag) {
            const int rl = q0 + mi * 32 + mt * 16 + quad * 4 + r;
            const int cl = s0 + ni * 96 + jn * 16 + l15;
            if (cl > rl) v = -1e30f;
          }
          sa[mt][jn][r] = v;
          pm[mt][r] = fmaxf(pm[mt][r], v);
        }
#pragma unroll
    for (int o = 1; o < 16; o <<= 1)
#pragma unroll
      for (int mt = 0; mt < 2; ++mt)
#pragma unroll
        for (int r = 0; r < 4; ++r)
          pm[mt][r] = fmaxf(pm[mt][r], __shfl_xor(pm[mt][r], o, 64));
    if (l15 == 0) {
#pragma unroll
      for (int mt = 0; mt < 2; ++mt)
#pragma unroll
        for (int r = 0; r < 4; ++r)
          pmax[ni][mi * 32 + mt * 16 + quad * 4 + r] = pm[mt][r];
    }
    __syncthreads();   // B1: pmax visible

    float al[2][4], ps[2][4];
#pragma unroll
    for (int mt = 0; mt < 2; ++mt)
#pragma unroll
      for (int r = 0; r < 4; ++r) {
        const int row = mi * 32 + mt * 16 + quad * 4 + r;
        const float mn = fmaxf(mrow[mt][r], fmaxf(pmax[0][row], pmax[1][row]));
        al[mt][r] = __builtin_amdgcn_exp2f(mrow[mt][r] - mn);
        mrow[mt][r] = mn;
        ps[mt][r] = 0.f;
      }
#pragma unroll
    for (int mt = 0; mt < 2; ++mt)
#pragma unroll
      for (int jn = 0; jn < 6; ++jn)
#pragma unroll
        for (int r = 0; r < 4; ++r) {
          const float e = __builtin_amdgcn_exp2f(sa[mt][jn][r] - mrow[mt][r]);
          ps[mt][r] += e;
          Ps[(mi * 32 + mt * 16 + quad * 4 + r) * 200 + ni * 96 + jn * 16 + l15] = (_Float16)e;
        }
#pragma unroll
    for (int o = 1; o < 16; o <<= 1)
#pragma unroll
      for (int mt = 0; mt < 2; ++mt)
#pragma unroll
        for (int r = 0; r < 4; ++r)
          ps[mt][r] += __shfl_xor(ps[mt][r], o, 64);
    if (l15 == 0) {
#pragma unroll
      for (int mt = 0; mt < 2; ++mt)
#pragma unroll
        for (int r = 0; r < 4; ++r)
          psum[ni][mi * 32 + mt * 16 + quad * 4 + r] = ps[mt][r];
    }
    __syncthreads();   // B2: Ps + psum visible

#pragma unroll
    for (int mt = 0; mt < 2; ++mt)
#pragma unroll
      for (int r = 0; r < 4; ++r) {
        const int row = mi * 32 + mt * 16 + quad * 4 + r;
        lrow[mt][r] = lrow[mt][r] * al[mt][r] + psum[0][row] + psum[1][row];
      }
#pragma unroll
    for (int mt = 0; mt < 2; ++mt)
#pragma unroll
      for (int nt = 0; nt < 8; ++nt)
#pragma unroll
        for (int r = 0; r < 4; ++r)
          acc_o[mt][nt][r] *= al[mt][r];

    // O += P @ V over 192 cols; P from LDS, V direct from global (L2-hot).
    // Slabs fully above the diagonal carry P==0 -> skip (wave-uniform).
#pragma unroll
    for (int kc2 = 0; kc2 < 6; ++kc2) {
      if (diag && (s0 + kc2 * 32 > q0 + 63)) continue;
      v8h pa[2];
#pragma unroll
      for (int mt = 0; mt < 2; ++mt) {
        const int row = mi * 32 + mt * 16 + l15;
        pa[mt] = *(const v8h*)(Ps + row * 200 + kc2 * 32 + quad * 8);
      }
#pragma unroll
      for (int nt = 0; nt < 8; ++nt) {
        const v8h vb = *(const v8h*)(vh + (long long)(ni * 128 + nt * 16 + l15) * 2048
                                     + s0 + kc2 * 32 + quad * 8);
#pragma unroll
        for (int mt = 0; mt < 2; ++mt)
          acc_o[mt][nt] = __builtin_amdgcn_mfma_f32_16x16x32_f16(pa[mt], vb, acc_o[mt][nt], 0, 0, 0);
      }
    }
    // no tail barrier: next-stage Ps/pmax writes are gated by B1/B2 above
  }

  // epilogue: O/l -> attn (r-part at 0, i-part at +2048*2048 floats)
#pragma unroll
  for (int mt = 0; mt < 2; ++mt) {
    float inv[4];
#pragma unroll
    for (int r = 0; r < 4; ++r) inv[r] = 1.f / lrow[mt][r];
#pragma unroll
    for (int nt = 0; nt < 8; ++nt) {
      const int d = ni * 128 + nt * 16 + l15;
      float* dst = attn + ((d < 128) ? 0ll : (2048ll * 2048)) + (h * 128 + (d & 127));
#pragma unroll
      for (int r = 0; r < 4; ++r) {
        const int t = q0 + mi * 32 + mt * 16 + quad * 4 + r;
        dst[(long long)t * 2048] = acc_o[mt][nt][r] * inv[r];
      }
    }
  }
}

extern "C" void kernel_launch(void* const* d_in, const int* in_sizes, int n_in,
                              void* d_out, int out_size, void* d_ws, size_t ws_size,
                              hipStream_t stream) {
  const float* hr   = (const float*)d_in[0];
  const float* hi   = (const float*)d_in[1];
  const int*   pos  = (const int*)d_in[2];
  const float* Wq_r = (const float*)d_in[3];
  const float* Wq_i = (const float*)d_in[4];
  const float* Wk_r = (const float*)d_in[5];
  const float* Wk_i = (const float*)d_in[6];
  const float* Wv_r = (const float*)d_in[7];
  const float* Wv_i = (const float*)d_in[8];
  const float* Wo_r = (const float*)d_in[9];
  const float* Wo_i = (const float*)d_in[10];

  char* ws = (char*)d_ws;
  _Float16* Bqkv = (_Float16*)(ws);                    // 96MB
  float*    attn = (float*)   (ws);                    // 32MB (alias, post-QKV)
  float*    cs   = (float*)   (ws + (32ll  << 20));    // 2MB  (alias, post-QKV)
  _Float16* Bo   = (_Float16*)(ws + (96ll  << 20));    // 32MB
  _Float16* Ac   = (_Float16*)(ws + (128ll << 20));    // 16MB
  _Float16* Yq   = (_Float16*)(ws + (144ll << 20));    // 32MB (q,k only)
  _Float16* qc   = (_Float16*)(ws + (176ll << 20));    // 16MB
  _Float16* kc   = (_Float16*)(ws + (192ll << 20));    // 16MB
  _Float16* vt   = (_Float16*)(ws + (208ll << 20));    // 16MB

  quant_rows<<<dim3(2048, 2), 256, 0, stream>>>(hr, hi, Ac);
  wprep<<<8192, 256, 0, stream>>>(Wq_r, Wq_i, Wk_r, Wk_i, Wv_r, Wv_i, Wo_r, Wo_i, Bqkv, Bo);
  // fused QKV: [qr|qi](2048x4096) @ Bqkv(12288x4096)^T -> Yq (q,k) + vt (v)
  gemm_qkv256<<<512, 512, 0, stream>>>(Ac, Bqkv, Yq, vt);
  trig_kernel<<<1024, 256, 0, stream>>>(pos, cs);
  rope_kernel<<<2048, 256, 0, stream>>>(Yq, cs, qc, kc);
  flash_attn<<<dim3(32, 16), 256, 0, stream>>>(qc, kc, vt, attn);
  quant_rows<<<dim3(2048, 2), 256, 0, stream>>>(attn, attn + 2048ll * 2048, Ac);
  // output projection -> d_out = [yr (T*H) | yi (T*H)] fp32
  gemm_out256<<<256, 512, 0, stream>>>(Ac, Bo, (float*)d_out);
}

// Round 11
// 709.617 us; speedup vs baseline: 1.5627x; 1.1490x over previous
//
#include <hip/hip_runtime.h>

// ComplexNetAttention on gfx950.
// Pipeline: int8-fakequant -> fused complex QKV GEMM (fp16 MFMA, NT, K=4096;
//   8-phase counted-vmcnt schedule, 256x192 tile) -> cos/sin table +
//   vectorized RoPE -> fused flash attention v2 (R15: KBLK=128 split-K z=2,
//   partials) -> combine -> fakequant -> out GEMM (256x128 8-phase).
//
// R15: R8/R9/R14 all spilled trying to raise flash occupancy via launch
// bounds / bigger tiles. The real cap was GRID SIZE: R7's flash (VGPR 116,
// LDS 18.4KB) is eligible for 4 blocks/CU but grid 512 = 2/CU. Split-K:
// blockIdx.z in {0,1} takes stages st = z, z+2, ... of the IDENTICAL R7
// stage structure (per-stage work/sync/VGPR unchanged), writes unnormalized
// O partials + per-row (m,l); fa_combine merges. Grid 1024 = 4 blocks/CU.

typedef float v4f __attribute__((ext_vector_type(4)));
typedef _Float16 v8h __attribute__((ext_vector_type(8)));
typedef _Float16 v4h __attribute__((ext_vector_type(4)));

typedef const __attribute__((address_space(1))) void glob_void;
typedef __attribute__((address_space(3))) void lds_void;

__device__ __forceinline__ void gload16(const _Float16* gp, _Float16* lp) {
  __builtin_amdgcn_global_load_lds((glob_void*)gp, (lds_void*)lp, 16, 0, 0);
}

// bf16 round-trip (RNE) in fp32 — matches reference's bf16 cos/sin cache.
__device__ __forceinline__ float bf16_rt(float f) {
  union { float f; unsigned u; } a; a.f = f;
  unsigned r = (a.u + 0x7fffu + ((a.u >> 16) & 1u)) & 0xffff0000u;
  union { unsigned u; float f; } b; b.u = r;
  return b.f;
}

#define SBAR()  __builtin_amdgcn_sched_barrier(0)
#define WBAR()  __builtin_amdgcn_s_barrier()
#define LGKM0() asm volatile("s_waitcnt lgkmcnt(0)" ::: "memory")

// ---------------------------------------------------------------------------
// QKV GEMM: C[2048][12288] = A[2048][4096] @ B[12288][4096]^T, fp16, fp32 acc.
// Tile 256x192, BK=64, 512 thr (8 waves 2m x 4n), wave-tile 128x48.
// 8-phase counted-vmcnt schedule (T3+T4), XOR chunk swizzle (0-conflict),
// s_setprio around MFMA clusters (T5), bijective XCD chunking (T1).
// ---------------------------------------------------------------------------
__global__ __launch_bounds__(512, 2) void gemm_qkv256(
    const _Float16* __restrict__ A, const _Float16* __restrict__ B,
    _Float16* __restrict__ Yq, _Float16* __restrict__ vt)
{
  const int p = blockIdx.x;            // 0..511, XCD = p & 7 (round-robin)
  const int xcd = p & 7, s = p >> 3;   // s: 0..63 within chunk
  const int mt = s & 7, ntl = s >> 3;
  const int nt = xcd * 8 + ntl;        // 0..63
  const int m0 = mt << 8;              // *256
  const int n0 = nt * 192;

  __shared__ __align__(16) _Float16 lds[57344];  // 2 bufs x (16384 A + 12288 B)

  const int tid = threadIdx.x, lane = tid & 63, wave = tid >> 6;
  const int quad = lane >> 4, l15 = lane & 15;
  const int wm = wave >> 2, wn = wave & 3;       // 2 x 4 waves

  const int rr = tid >> 2;                                   // 0..127
  const int lc8 = (((tid & 3) ^ ((tid >> 3) & 3)) << 3);     // logical chunk*8
  const _Float16* gA = A + (long long)(m0 + rr) * 4096 + lc8;
  const _Float16* gBj[3];
#pragma unroll
  for (int j = 0; j < 3; ++j) {
    const int ks = (j == 2) || (j == 1 && tid >= 256);
    const int r = j * 128 + (tid >> 2) - ks * 192;
    gBj[j] = B + (long long)(n0 + r) * 4096 + ks * 32 + lc8;
  }

  const int co = ((quad ^ ((l15 >> 1) & 3)) << 3);
  const int aBase = (wm * 128 + l15) * 32 + co;
  const int bBase = (wn * 48 + l15) * 32 + co;

  v4f acc[8][3] = {};

  // prologue: stage tile 0 -> buf 0 in canonical order a0,a1,b0,b1,a2,a3,b2
  {
    _Float16* sd = lds + tid * 8;
    gload16(gA, sd);
    gload16(gA + 524288, sd + 4096);          // 128*4096
    gload16(gBj[0], sd + 16384);
    gload16(gBj[1], sd + 20480);
    gload16(gA + 32, sd + 8192);
    gload16(gA + 524288 + 32, sd + 12288);
    gload16(gBj[2], sd + 24576);
  }
  asm volatile("s_waitcnt vmcnt(3)" ::: "memory");  // first-4 of tile 0 done
  WBAR();

  for (int t = 0; t < 64; ++t) {
    const _Float16* As = lds + (t & 1) * 28672;
    const _Float16* Bs = As + 16384;
    _Float16* sd = lds + ((t & 1) ^ 1) * 28672 + tid * 8;
    const int k1 = (t + 1) << 6;
    const bool stg = (t < 63);

    v8h bf[3], af[4];

    // ===== P0: ds bf(ks0)+af(mh0,ks0); stage a0,a1(t+1) =====
    af[0] = *(const v8h*)&As[aBase];
    af[1] = *(const v8h*)&As[aBase + 512];
    af[2] = *(const v8h*)&As[aBase + 1024];
    af[3] = *(const v8h*)&As[aBase + 1536];
    bf[0] = *(const v8h*)&Bs[bBase];
    bf[1] = *(const v8h*)&Bs[bBase + 512];
    bf[2] = *(const v8h*)&Bs[bBase + 1024];
    if (stg) { gload16(gA + k1, sd); gload16(gA + k1 + 524288, sd + 4096); }
    SBAR(); WBAR(); LGKM0(); SBAR();
    __builtin_amdgcn_s_setprio(1);
#pragma unroll
    for (int i = 0; i < 4; ++i)
#pragma unroll
      for (int nf = 0; nf < 3; ++nf)
        acc[i][nf] = __builtin_amdgcn_mfma_f32_16x16x32_f16(af[i], bf[nf], acc[i][nf], 0, 0, 0);
    __builtin_amdgcn_s_setprio(0);
    WBAR();

    // ===== P1: ds af(mh1,ks0); stage b0,b1(t+1); vmcnt(4) =====
    af[0] = *(const v8h*)&As[aBase + 2048];
    af[1] = *(const v8h*)&As[aBase + 2560];
    af[2] = *(const v8h*)&As[aBase + 3072];
    af[3] = *(const v8h*)&As[aBase + 3584];
    if (stg) { gload16(gBj[0] + k1, sd + 16384); gload16(gBj[1] + k1, sd + 20480); }
    SBAR(); WBAR(); LGKM0(); SBAR();
    __builtin_amdgcn_s_setprio(1);
#pragma unroll
    for (int i = 0; i < 4; ++i)
#pragma unroll
      for (int nf = 0; nf < 3; ++nf)
        acc[4 + i][nf] = __builtin_amdgcn_mfma_f32_16x16x32_f16(af[i], bf[nf], acc[4 + i][nf], 0, 0, 0);
    __builtin_amdgcn_s_setprio(0);
    if (stg) asm volatile("s_waitcnt vmcnt(4)" ::: "memory");
    else     asm volatile("s_waitcnt vmcnt(0)" ::: "memory");
    WBAR();

    // ===== P2: ds bf(ks1)+af(mh0,ks1); stage a2,a3(t+1) =====
    bf[0] = *(const v8h*)&Bs[bBase + 6144];
    bf[1] = *(const v8h*)&Bs[bBase + 6656];
    bf[2] = *(const v8h*)&Bs[bBase + 7168];
    af[0] = *(const v8h*)&As[aBase + 8192];
    af[1] = *(const v8h*)&As[aBase + 8704];
    af[2] = *(const v8h*)&As[aBase + 9216];
    af[3] = *(const v8h*)&As[aBase + 9728];
    if (stg) { gload16(gA + k1 + 32, sd + 8192); gload16(gA + k1 + 524288 + 32, sd + 12288); }
    SBAR(); WBAR(); LGKM0(); SBAR();
    __builtin_amdgcn_s_setprio(1);
#pragma unroll
    for (int i = 0; i < 4; ++i)
#pragma unroll
      for (int nf = 0; nf < 3; ++nf)
        acc[i][nf] = __builtin_amdgcn_mfma_f32_16x16x32_f16(af[i], bf[nf], acc[i][nf], 0, 0, 0);
    __builtin_amdgcn_s_setprio(0);
    WBAR();

    // ===== P3: ds af(mh1,ks1); stage b2(t+1); vmcnt(3) =====
    af[0] = *(const v8h*)&As[aBase + 10240];
    af[1] = *(const v8h*)&As[aBase + 10752];
    af[2] = *(const v8h*)&As[aBase + 11264];
    af[3] = *(const v8h*)&As[aBase + 11776];
    if (stg) gload16(gBj[2] + k1, sd + 24576);
    SBAR(); WBAR(); LGKM0(); SBAR();
    __builtin_amdgcn_s_setprio(1);
#pragma unroll
    for (int i = 0; i < 4; ++i)
#pragma unroll
      for (int nf = 0; nf < 3; ++nf)
        acc[4 + i][nf] = __builtin_amdgcn_mfma_f32_16x16x32_f16(af[i], bf[nf], acc[4 + i][nf], 0, 0, 0);
    __builtin_amdgcn_s_setprio(0);
    if (stg) asm volatile("s_waitcnt vmcnt(3)" ::: "memory");
    WBAR();
  }

  // epilogue: C/D layout col=lane&15, row=quad*4+reg (m89/m91-verified)
#pragma unroll
  for (int mf = 0; mf < 8; ++mf) {
#pragma unroll
    for (int nf = 0; nf < 3; ++nf) {
      const int col = n0 + wn * 48 + nf * 16 + l15;
      const int row0 = m0 + wm * 128 + mf * 16 + quad * 4;   // multiple of 4
      if (col >= 8192) {
        // v projection -> vt[NH][256][2048], packed 4 rows per store
        const int c = col - 8192;
        const int hh = (c & 2047) >> 7;
        const int dcol = (c < 2048) ? (c & 127) : (128 + (c & 127));
        v4h pk;
#pragma unroll
        for (int r = 0; r < 4; ++r) pk[r] = (_Float16)acc[mf][nf][r];
        *(v4h*)(vt + ((long long)(hh * 256 + dcol)) * 2048 + row0) = pk;
      } else {
#pragma unroll
        for (int r = 0; r < 4; ++r)
          Yq[(long long)(row0 + r) * 8192 + col] = (_Float16)acc[mf][nf][r];
      }
    }
  }
}

// ---------------------------------------------------------------------------
// Out GEMM: O[2048][4096] = A[2048][4096] @ B[4096][4096]^T, fp32 out,
// split cols [yr|yi] into concatenated halves of d_out.
// 256x128 tile, BK=64, 8-phase counted-vmcnt (proven R10). Grid 256 = 1/CU.
// ---------------------------------------------------------------------------
__global__ __launch_bounds__(512, 2) void gemm_out256(
    const _Float16* __restrict__ A, const _Float16* __restrict__ B,
    float* __restrict__ O)
{
  const int p = blockIdx.x;            // 0..255
  const int xcd = p & 7, s = p >> 3;   // s: 0..31
  const int mt = s & 7, ntl = s >> 3;  // 8 m-tiles, 4 n-tiles per XCD
  const int nt = xcd * 4 + ntl;        // 0..31
  const int m0 = mt << 8, n0 = nt << 7;

  __shared__ __align__(16) _Float16 lds[49152];  // 2 bufs x (16384 A + 8192 B)

  const int tid = threadIdx.x, lane = tid & 63, wave = tid >> 6;
  const int quad = lane >> 4, l15 = lane & 15;
  const int wm = wave >> 2, wn = wave & 3;       // 2 x 4 waves

  const int rr = tid >> 2;                                   // 0..127
  const int lc8 = (((tid & 3) ^ ((tid >> 3) & 3)) << 3);     // logical chunk*8
  const _Float16* gA = A + (long long)(m0 + rr) * 4096 + lc8;
  const _Float16* gB = B + (long long)(n0 + rr) * 4096 + lc8;

  const int co = ((quad ^ ((l15 >> 1) & 3)) << 3);
  const int aBase = (wm * 128 + l15) * 32 + co;
  const int bBase = (wn * 32 + l15) * 32 + co;

  v4f acc[8][2] = {};

  // prologue: stage tile 0 -> buf 0, first-half trio first
  {
    _Float16* sd = lds + tid * 8;
    gload16(gA, sd);                        // a0: rows 0-127, ks0
    gload16(gA + 524288, sd + 4096);        // a1: rows 128-255, ks0
    gload16(gB, sd + 16384);                // b0: ks0
    gload16(gA + 32, sd + 8192);            // a2: rows 0-127, ks1
    gload16(gA + 524288 + 32, sd + 12288);  // a3: rows 128-255, ks1
    gload16(gB + 32, sd + 20480);           // b1: ks1
  }
  asm volatile("s_waitcnt vmcnt(3)" ::: "memory");  // first trio of tile 0
  WBAR();

  for (int t = 0; t < 64; ++t) {
    const _Float16* As = lds + (t & 1) * 24576;
    const _Float16* Bs = As + 16384;
    _Float16* sd = lds + ((t & 1) ^ 1) * 24576 + tid * 8;
    const int k1 = (t + 1) << 6;
    const bool stg = (t < 63);

    v8h bf[2], af[4];

    // ===== P0: ds af(mh0,ks0)+bf(ks0); stage a0,a1(t+1) =====
    af[0] = *(const v8h*)&As[aBase];
    af[1] = *(const v8h*)&As[aBase + 512];
    af[2] = *(const v8h*)&As[aBase + 1024];
    af[3] = *(const v8h*)&As[aBase + 1536];
    bf[0] = *(const v8h*)&Bs[bBase];
    bf[1] = *(const v8h*)&Bs[bBase + 512];
    if (stg) { gload16(gA + k1, sd); gload16(gA + k1 + 524288, sd + 4096); }
    SBAR(); WBAR(); LGKM0(); SBAR();
    __builtin_amdgcn_s_setprio(1);
#pragma unroll
    for (int i = 0; i < 4; ++i)
#pragma unroll
      for (int nf = 0; nf < 2; ++nf)
        acc[i][nf] = __builtin_amdgcn_mfma_f32_16x16x32_f16(af[i], bf[nf], acc[i][nf], 0, 0, 0);
    __builtin_amdgcn_s_setprio(0);
    WBAR();

    // ===== P1: ds af(mh1,ks0); stage b0(t+1); vmcnt(3) =====
    af[0] = *(const v8h*)&As[aBase + 2048];
    af[1] = *(const v8h*)&As[aBase + 2560];
    af[2] = *(const v8h*)&As[aBase + 3072];
    af[3] = *(const v8h*)&As[aBase + 3584];
    if (stg) gload16(gB + k1, sd + 16384);
    SBAR(); WBAR(); LGKM0(); SBAR();
    __builtin_amdgcn_s_setprio(1);
#pragma unroll
    for (int i = 0; i < 4; ++i)
#pragma unroll
      for (int nf = 0; nf < 2; ++nf)
        acc[4 + i][nf] = __builtin_amdgcn_mfma_f32_16x16x32_f16(af[i], bf[nf], acc[4 + i][nf], 0, 0, 0);
    __builtin_amdgcn_s_setprio(0);
    if (stg) asm volatile("s_waitcnt vmcnt(3)" ::: "memory");
    else     asm volatile("s_waitcnt vmcnt(0)" ::: "memory");
    WBAR();

    // ===== P2: ds bf(ks1)+af(mh0,ks1); stage a2,a3(t+1) =====
    bf[0] = *(const v8h*)&Bs[bBase + 4096];
    bf[1] = *(const v8h*)&Bs[bBase + 4608];
    af[0] = *(const v8h*)&As[aBase + 8192];
    af[1] = *(const v8h*)&As[aBase + 8704];
    af[2] = *(const v8h*)&As[aBase + 9216];
    af[3] = *(const v8h*)&As[aBase + 9728];
    if (stg) { gload16(gA + k1 + 32, sd + 8192); gload16(gA + k1 + 524288 + 32, sd + 12288); }
    SBAR(); WBAR(); LGKM0(); SBAR();
    __builtin_amdgcn_s_setprio(1);
#pragma unroll
    for (int i = 0; i < 4; ++i)
#pragma unroll
      for (int nf = 0; nf < 2; ++nf)
        acc[i][nf] = __builtin_amdgcn_mfma_f32_16x16x32_f16(af[i], bf[nf], acc[i][nf], 0, 0, 0);
    __builtin_amdgcn_s_setprio(0);
    WBAR();

    // ===== P3: ds af(mh1,ks1); stage b1(t+1); vmcnt(3) =====
    af[0] = *(const v8h*)&As[aBase + 10240];
    af[1] = *(const v8h*)&As[aBase + 10752];
    af[2] = *(const v8h*)&As[aBase + 11264];
    af[3] = *(const v8h*)&As[aBase + 11776];
    if (stg) gload16(gB + k1 + 32, sd + 20480);
    SBAR(); WBAR(); LGKM0(); SBAR();
    __builtin_amdgcn_s_setprio(1);
#pragma unroll
    for (int i = 0; i < 4; ++i)
#pragma unroll
      for (int nf = 0; nf < 2; ++nf)
        acc[4 + i][nf] = __builtin_amdgcn_mfma_f32_16x16x32_f16(af[i], bf[nf], acc[4 + i][nf], 0, 0, 0);
    __builtin_amdgcn_s_setprio(0);
    if (stg) asm volatile("s_waitcnt vmcnt(3)" ::: "memory");
    WBAR();
  }

  // epilogue: fp32, split cols [yr|yi] into concatenated halves of d_out
#pragma unroll
  for (int mf = 0; mf < 8; ++mf) {
#pragma unroll
    for (int nf = 0; nf < 2; ++nf) {
      const int col = n0 + wn * 32 + nf * 16 + l15;
      const int row0 = m0 + wm * 128 + mf * 16 + quad * 4;
#pragma unroll
      for (int r = 0; r < 4; ++r) {
        const int row = row0 + r;
        const float v = acc[mf][nf][r];
        if (col < 2048) O[(long long)row * 2048 + col] = v;
        else O[2048ll * 2048 + (long long)row * 2048 + (col - 2048)] = v;
      }
    }
  }
}

// per-row int8 fake-quant of two [2048][2048] fp32 sources -> fp16 [2048][4096]
__global__ __launch_bounds__(256) void quant_rows(
    const float* __restrict__ s0, const float* __restrict__ s1,
    _Float16* __restrict__ dst)
{
  const int t = blockIdx.x, y = blockIdx.y;
  const float* src = (y ? s1 : s0) + (long long)t * 2048;
  const int tid = threadIdx.x, lane = tid & 63, wave = tid >> 6;
  __shared__ float rbuf[4];
  const v4f a = *(const v4f*)(src + tid * 4);
  const v4f b = *(const v4f*)(src + 1024 + tid * 4);
  float m = 0.f;
#pragma unroll
  for (int k = 0; k < 4; ++k)
    m = fmaxf(m, fmaxf(fabsf(a[k]), fabsf(b[k])));
  for (int o = 1; o < 64; o <<= 1) m = fmaxf(m, __shfl_xor(m, o, 64));
  if (lane == 0) rbuf[wave] = m;
  __syncthreads();
  m = fmaxf(fmaxf(rbuf[0], rbuf[1]), fmaxf(rbuf[2], rbuf[3]));
  const float scale = 127.f / fmaxf(m, 1e-5f);
  const float inv = 1.f / scale;
  _Float16* d = dst + (long long)t * 4096 + (long long)y * 2048 + tid * 4;
  v4h qa, qb;
#pragma unroll
  for (int k = 0; k < 4; ++k) {
    qa[k] = (_Float16)(fminf(fmaxf(rintf(a[k] * scale), -128.f), 127.f) * inv);
    qb[k] = (_Float16)(fminf(fmaxf(rintf(b[k] * scale), -128.f), 127.f) * inv);
  }
  *(v4h*)d = qa;
  *(v4h*)(d + 1024) = qb;
}

// Build concatenated complex weight matrices (fp16)
__global__ __launch_bounds__(256) void wprep(
    const float* __restrict__ Wq_r, const float* __restrict__ Wq_i,
    const float* __restrict__ Wk_r, const float* __restrict__ Wk_i,
    const float* __restrict__ Wv_r, const float* __restrict__ Wv_i,
    const float* __restrict__ Wo_r, const float* __restrict__ Wo_i,
    _Float16* __restrict__ Bqkv, _Float16* __restrict__ Bo)
{
  const float* Ws[8] = {Wq_r, Wq_i, Wk_r, Wk_i, Wv_r, Wv_i, Wo_r, Wo_i};
  const int i = blockIdx.x * 256 + threadIdx.x;
  const int w = i >> 18;
  const int rem = i & 262143;
  const int j = rem >> 7;
  const int cb = (rem & 127) * 16;
  const float* src = Ws[w] + (long long)j * 2048 + cb;
  _Float16* Bp = (w < 6) ? (Bqkv + (long long)(w >> 1) * 4096 * 4096) : Bo;
  const int isI = w & 1;
  _Float16* d1 = Bp + (long long)j * 4096 + (isI ? 2048 + cb : cb);
  _Float16* d2 = Bp + (long long)(2048 + j) * 4096 + (isI ? cb : 2048 + cb);
  const float sg2 = isI ? 1.f : -1.f;
#pragma unroll
  for (int q = 0; q < 4; ++q) {
    const v4f v = *(const v4f*)(src + q * 4);
    v4h o1, o2;
#pragma unroll
    for (int k = 0; k < 4; ++k) {
      o1[k] = (_Float16)v[k];
      o2[k] = (_Float16)(v[k] * sg2);
    }
    *(v4h*)(d1 + q * 4) = o1;
    *(v4h*)(d2 + q * 4) = o2;
  }
}

// cos/sin table [T][128] float2, bf16-rounded
__global__ __launch_bounds__(256) void trig_kernel(
    const int* __restrict__ pos, float* __restrict__ cs)
{
  const int t = blockIdx.x * 2 + (threadIdx.x >> 7);
  const int d = threadIdx.x & 127;
  const float invf = (float)pow(10000.0, -(double)d / 128.0);
  const float fr = (float)pos[t] * invf;
  const double fd = (double)fr;
  cs[((long long)t * 128 + d) * 2]     = bf16_rt((float)cos(fd));
  cs[((long long)t * 128 + d) * 2 + 1] = bf16_rt((float)sin(fd));
}

// vectorized RoPE: Yq [T][8192] (qr|qi|kr|ki) -> qc/kc [NH][T][256] fp16
__global__ __launch_bounds__(256) void rope_kernel(
    const _Float16* __restrict__ Yq, const float* __restrict__ cs,
    _Float16* __restrict__ qc, _Float16* __restrict__ kc)
{
  const int idx = blockIdx.x * 256 + threadIdx.x;
  const int d0 = (idx & 15) * 8;
  const int h  = (idx >> 4) & 15;
  const int t  = idx >> 8;
  const _Float16* y = Yq + (long long)t * 8192 + h * 128 + d0;
  const v8h qr8 = *(const v8h*)(y);
  const v8h qi8 = *(const v8h*)(y + 2048);
  const v8h kr8 = *(const v8h*)(y + 4096);
  const v8h ki8 = *(const v8h*)(y + 6144);
  const float* cp = cs + ((long long)t * 128 + d0) * 2;
  v8h qro, qio, kro, kio;
#pragma unroll
  for (int u = 0; u < 8; ++u) {
    const float c = cp[u * 2], s = cp[u * 2 + 1];
    const float qr = (float)qr8[u], qi = (float)qi8[u];
    const float kr = (float)kr8[u], ki = (float)ki8[u];
    qro[u] = (_Float16)(qr * c - qi * s);
    qio[u] = (_Float16)(qi * c + qr * s);
    kro[u] = (_Float16)(kr * c - ki * s);
    kio[u] = (_Float16)(ki * c + kr * s);
  }
  _Float16* qo = qc + ((long long)h * 2048 + t) * 256 + d0;
  _Float16* ko = kc + ((long long)h * 2048 + t) * 256 + d0;
  *(v8h*)qo = qro; *(v8h*)(qo + 128) = qio;
  *(v8h*)ko = kro; *(v8h*)(ko + 128) = kio;
}

// Fused causal flash attention v2 — R7 structure (KBLK=128), split-K z=2.
// One block = 64 Q-rows of one head, 4 waves as 2(m)x2(n: 64-col halves),
// stages st = z, z+2, ... (per-stage work/sync identical to R7's 686us
// version). Writes UNNORMALIZED O partials + per-row (m,l) in exp2 domain;
// fa_combine merges. Grid 32x16x2 = 1024 blocks = 4 resident blocks/CU
// (VGPR 116 <= 128 -> 4 waves/SIMD; LDS 18.4KB x4 = 74KB).
__global__ __launch_bounds__(256, 2) void flash_attn(
    const _Float16* __restrict__ qc, const _Float16* __restrict__ kc,
    const _Float16* __restrict__ vt, float* __restrict__ opart,
    float* __restrict__ ml)
{
  __shared__ __align__(16) _Float16 Ps[64 * 136];  // 128 cols, pad ->136
  __shared__ float pmax[2][64];
  __shared__ float psum[2][64];

  const int h  = blockIdx.y;
  const int z  = blockIdx.z;
  // load-balance remap: pair small-qt with large-qt across heads
  const int qt = ((h >> 3) & 1) ? (31 - (int)blockIdx.x) : (int)blockIdx.x;
  const int q0 = qt * 64;
  const int tid = threadIdx.x, lane = tid & 63, wave = tid >> 6;
  const int mi = wave >> 1, ni = wave & 1;
  const int quad = lane >> 4, l15 = lane & 15;

  const _Float16* qh = qc + (long long)h * 2048 * 256;
  const _Float16* kh = kc + (long long)h * 2048 * 256;
  const _Float16* vh = vt + (long long)h * 256 * 2048;

  // Q fragments in registers, pre-scaled by log2(e)/16 (exp2-domain softmax)
  const _Float16 scl = (_Float16)0.09016844f;
  v8h qf[2][8];
#pragma unroll
  for (int mt = 0; mt < 2; ++mt) {
    const int t = q0 + mi * 32 + mt * 16 + l15;
#pragma unroll
    for (int ks = 0; ks < 8; ++ks) {
      v8h q = *(const v8h*)(qh + (long long)t * 256 + ks * 32 + quad * 8);
#pragma unroll
      for (int u = 0; u < 8; ++u) q[u] *= scl;
      qf[mt][ks] = q;
    }
  }

  float mrow[2][4], lrow[2][4];
  v4f acc_o[2][8];
#pragma unroll
  for (int mt = 0; mt < 2; ++mt)
#pragma unroll
    for (int r = 0; r < 4; ++r) { mrow[mt][r] = -1e30f; lrow[mt][r] = 0.f; }
#pragma unroll
  for (int mt = 0; mt < 2; ++mt)
#pragma unroll
    for (int nt = 0; nt < 8; ++nt) acc_o[mt][nt] = (v4f){0.f, 0.f, 0.f, 0.f};

  const int nst = (qt >> 1) + 1;
  for (int st = z; st < nst; st += 2) {
    const int s0 = st * 128;
    const bool diag = (st == nst - 1);

    // wave-uniform liveness of each 16-col jn tile (cols fully above diag?)
    bool live[4];
#pragma unroll
    for (int jn = 0; jn < 4; ++jn)
      live[jn] = !diag || (s0 + ni * 64 + jn * 16 <= q0 + 63);

    // S half = Q @ K[128 cols; this wave's 64-col half]^T, K direct from L2
    v4f sa[2][4] = {};
#pragma unroll
    for (int ks = 0; ks < 8; ++ks) {
      v8h bk[4];
#pragma unroll
      for (int jn = 0; jn < 4; ++jn)
        if (live[jn])
          bk[jn] = *(const v8h*)(kh + (long long)(s0 + ni * 64 + jn * 16 + l15) * 256
                                 + ks * 32 + quad * 8);
#pragma unroll
      for (int mt = 0; mt < 2; ++mt)
#pragma unroll
        for (int jn = 0; jn < 4; ++jn)
          if (live[jn])
            sa[mt][jn] = __builtin_amdgcn_mfma_f32_16x16x32_f16(qf[mt][ks], bk[jn], sa[mt][jn], 0, 0, 0);
    }

    float pm[2][4];
#pragma unroll
    for (int mt = 0; mt < 2; ++mt)
#pragma unroll
      for (int r = 0; r < 4; ++r) pm[mt][r] = -1e30f;
#pragma unroll
    for (int mt = 0; mt < 2; ++mt)
#pragma unroll
      for (int jn = 0; jn < 4; ++jn)
#pragma unroll
        for (int r = 0; r < 4; ++r) {
          float v = sa[mt][jn][r];          // already log2-scaled
          if (diag) {
            const int rl = q0 + mi * 32 + mt * 16 + quad * 4 + r;
            const int cl = s0 + ni * 64 + jn * 16 + l15;
            if (cl > rl) v = -1e30f;
          }
          sa[mt][jn][r] = v;
          pm[mt][r] = fmaxf(pm[mt][r], v);
        }
#pragma unroll
    for (int o = 1; o < 16; o <<= 1)
#pragma unroll
      for (int mt = 0; mt < 2; ++mt)
#pragma unroll
        for (int r = 0; r < 4; ++r)
          pm[mt][r] = fmaxf(pm[mt][r], __shfl_xor(pm[mt][r], o, 64));
    if (l15 == 0) {
#pragma unroll
      for (int mt = 0; mt < 2; ++mt)
#pragma unroll
        for (int r = 0; r < 4; ++r)
          pmax[ni][mi * 32 + mt * 16 + quad * 4 + r] = pm[mt][r];
    }
    __syncthreads();   // B1: pmax visible

    float al[2][4], ps[2][4];
#pragma unroll
    for (int mt = 0; mt < 2; ++mt)
#pragma unroll
      for (int r = 0; r < 4; ++r) {
        const int row = mi * 32 + mt * 16 + quad * 4 + r;
        const float mn = fmaxf(mrow[mt][r], fmaxf(pmax[0][row], pmax[1][row]));
        al[mt][r] = __builtin_amdgcn_exp2f(mrow[mt][r] - mn);
        mrow[mt][r] = mn;
        ps[mt][r] = 0.f;
      }
#pragma unroll
    for (int mt = 0; mt < 2; ++mt)
#pragma unroll
      for (int jn = 0; jn < 4; ++jn)
#pragma unroll
        for (int r = 0; r < 4; ++r) {
          const float e = __builtin_amdgcn_exp2f(sa[mt][jn][r] - mrow[mt][r]);
          ps[mt][r] += e;
          Ps[(mi * 32 + mt * 16 + quad * 4 + r) * 136 + ni * 64 + jn * 16 + l15] = (_Float16)e;
        }
#pragma unroll
    for (int o = 1; o < 16; o <<= 1)
#pragma unroll
      for (int mt = 0; mt < 2; ++mt)
#pragma unroll
        for (int r = 0; r < 4; ++r)
          ps[mt][r] += __shfl_xor(ps[mt][r], o, 64);
    if (l15 == 0) {
#pragma unroll
      for (int mt = 0; mt < 2; ++mt)
#pragma unroll
        for (int r = 0; r < 4; ++r)
          psum[ni][mi * 32 + mt * 16 + quad * 4 + r] = ps[mt][r];
    }
    __syncthreads();   // B2: Ps + psum visible

#pragma unroll
    for (int mt = 0; mt < 2; ++mt)
#pragma unroll
      for (int r = 0; r < 4; ++r) {
        const int row = mi * 32 + mt * 16 + quad * 4 + r;
        lrow[mt][r] = lrow[mt][r] * al[mt][r] + psum[0][row] + psum[1][row];
      }
#pragma unroll
    for (int mt = 0; mt < 2; ++mt)
#pragma unroll
      for (int nt = 0; nt < 8; ++nt)
#pragma unroll
        for (int r = 0; r < 4; ++r)
          acc_o[mt][nt][r] *= al[mt][r];

    // O += P @ V over 128 cols; P from LDS, V direct from global (L2-hot).
    // Slabs fully above the diagonal carry P==0 -> skip (wave-uniform).
#pragma unroll
    for (int kc2 = 0; kc2 < 4; ++kc2) {
      if (diag && (s0 + kc2 * 32 > q0 + 63)) continue;
      v8h pa[2];
#pragma unroll
      for (int mt = 0; mt < 2; ++mt) {
        const int row = mi * 32 + mt * 16 + l15;
        pa[mt] = *(const v8h*)(Ps + row * 136 + kc2 * 32 + quad * 8);
      }
#pragma unroll
      for (int nt = 0; nt < 8; ++nt) {
        const v8h vb = *(const v8h*)(vh + (long long)(ni * 128 + nt * 16 + l15) * 2048
                                     + s0 + kc2 * 32 + quad * 8);
#pragma unroll
        for (int mt = 0; mt < 2; ++mt)
          acc_o[mt][nt] = __builtin_amdgcn_mfma_f32_16x16x32_f16(pa[mt], vb, acc_o[mt][nt], 0, 0, 0);
      }
    }
    // no tail barrier: next-stage Ps/pmax writes are gated by B1/B2 above
  }

  // epilogue: UNNORMALIZED partials -> opart[z][h][t][256], (m,l) -> ml
  float* Od = opart + (long long)(z * 16 + h) * 2048 * 256;
  if (ni == 0 && l15 == 0) {
    float2* mlp = (float2*)ml + (long long)(z * 16 + h) * 2048;
#pragma unroll
    for (int mt = 0; mt < 2; ++mt)
#pragma unroll
      for (int r = 0; r < 4; ++r) {
        const int t = q0 + mi * 32 + mt * 16 + quad * 4 + r;
        mlp[t] = make_float2(mrow[mt][r], lrow[mt][r]);
      }
  }
#pragma unroll
  for (int mt = 0; mt < 2; ++mt)
#pragma unroll
    for (int nt = 0; nt < 8; ++nt) {
      const int d = ni * 128 + nt * 16 + l15;
#pragma unroll
      for (int r = 0; r < 4; ++r) {
        const int t = q0 + mi * 32 + mt * 16 + quad * 4 + r;
        Od[(long long)t * 256 + d] = acc_o[mt][nt][r];
      }
    }
}

// combine the two split-K partials: O = (O0*w0 + O1*w1) / (l0*w0 + l1*w1),
// w_z = exp2(m_z - max(m0,m1)); writes attn layout (r at 0, i at +T*T).
__global__ __launch_bounds__(256) void fa_combine(
    const float* __restrict__ opart, const float* __restrict__ ml,
    float* __restrict__ attn)
{
  const int idx = blockIdx.x * 256 + threadIdx.x;  // 16h x 2048t x 64 d4grp
  const int d4 = (idx & 63) * 4;
  const int t  = (idx >> 6) & 2047;
  const int h  = idx >> 17;
  const float2 a = ((const float2*)ml)[h * 2048 + t];
  const float2 b = ((const float2*)ml)[(16 + h) * 2048 + t];
  const float ms = fmaxf(a.x, b.x);
  const float w0 = __builtin_amdgcn_exp2f(a.x - ms);
  const float w1 = __builtin_amdgcn_exp2f(b.x - ms);
  const float inv = 1.f / (a.y * w0 + b.y * w1);
  const v4f o0 = *(const v4f*)(opart + ((long long)h * 2048 + t) * 256 + d4);
  const v4f o1 = *(const v4f*)(opart + ((long long)(16 + h) * 2048 + t) * 256 + d4);
  v4f o;
#pragma unroll
  for (int k = 0; k < 4; ++k) o[k] = (o0[k] * w0 + o1[k] * w1) * inv;
  float* dst = attn + ((d4 < 128) ? 0ll : (2048ll * 2048))
             + (long long)t * 2048 + h * 128 + (d4 & 127);
  *(v4f*)dst = o;
}

extern "C" void kernel_launch(void* const* d_in, const int* in_sizes, int n_in,
                              void* d_out, int out_size, void* d_ws, size_t ws_size,
                              hipStream_t stream) {
  const float* hr   = (const float*)d_in[0];
  const float* hi   = (const float*)d_in[1];
  const int*   pos  = (const int*)d_in[2];
  const float* Wq_r = (const float*)d_in[3];
  const float* Wq_i = (const float*)d_in[4];
  const float* Wk_r = (const float*)d_in[5];
  const float* Wk_i = (const float*)d_in[6];
  const float* Wv_r = (const float*)d_in[7];
  const float* Wv_i = (const float*)d_in[8];
  const float* Wo_r = (const float*)d_in[9];
  const float* Wo_i = (const float*)d_in[10];

  char* ws = (char*)d_ws;
  _Float16* Bqkv  = (_Float16*)(ws);                   // 96MB
  float*    attn  = (float*)   (ws);                   // 32MB (alias, post-QKV)
  float*    cs    = (float*)   (ws + (32ll  << 20));   // 2MB  (alias, post-QKV)
  float*    opart = (float*)   (ws + (32ll  << 20));   // 64MB (alias, post-rope)
  _Float16* Bo    = (_Float16*)(ws + (96ll  << 20));   // 32MB
  _Float16* Ac    = (_Float16*)(ws + (128ll << 20));   // 16MB
  _Float16* Yq    = (_Float16*)(ws + (144ll << 20));   // 32MB (q,k only)
  float*    mlbuf = (float*)   (ws + (144ll << 20));   // 512KB (alias, post-rope)
  _Float16* qc    = (_Float16*)(ws + (176ll << 20));   // 16MB
  _Float16* kc    = (_Float16*)(ws + (192ll << 20));   // 16MB
  _Float16* vt    = (_Float16*)(ws + (208ll << 20));   // 16MB

  quant_rows<<<dim3(2048, 2), 256, 0, stream>>>(hr, hi, Ac);
  wprep<<<8192, 256, 0, stream>>>(Wq_r, Wq_i, Wk_r, Wk_i, Wv_r, Wv_i, Wo_r, Wo_i, Bqkv, Bo);
  // fused QKV: [qr|qi](2048x4096) @ Bqkv(12288x4096)^T -> Yq (q,k) + vt (v)
  gemm_qkv256<<<512, 512, 0, stream>>>(Ac, Bqkv, Yq, vt);
  trig_kernel<<<1024, 256, 0, stream>>>(pos, cs);
  rope_kernel<<<2048, 256, 0, stream>>>(Yq, cs, qc, kc);
  flash_attn<<<dim3(32, 16, 2), 256, 0, stream>>>(qc, kc, vt, opart, mlbuf);
  fa_combine<<<8192, 256, 0, stream>>>(opart, mlbuf, attn);
  quant_rows<<<dim3(2048, 2), 256, 0, stream>>>(attn, attn + 2048ll * 2048, Ac);
  // output projection -> d_out = [yr (T*H) | yi (T*H)] fp32
  gemm_out256<<<256, 512, 0, stream>>>(Ac, Bo, (float*)d_out);
}